// Round 1
// baseline (1313.107 us; speedup 1.0000x reference)
//
#include <hip/hip_runtime.h>
#include <hip/hip_bf16.h>
#include <math.h>

#define Bq   32
#define Tt   1024
#define Hh   512
#define Vv   1024
#define Ss   128
#define Lext 257
#define NEGF (-1e30f)

// ---------------- GEMM: C = act(A @ B + bias), fp32, 128x128 tile ----------------
template<bool TANH>
__global__ __launch_bounds__(256)
void gemm_bias_act(const float* __restrict__ A, const float* __restrict__ Bm,
                   const float* __restrict__ bias, float* __restrict__ C,
                   int M, int N, int K) {
  __shared__ float As[8][128];   // transposed: As[k][m]
  __shared__ float Bs[8][128];   // Bs[k][n]
  const int tid = threadIdx.x;
  const int tx = tid & 15, ty = tid >> 4;
  const int row0 = blockIdx.y * 128;
  const int col0 = blockIdx.x * 128;
  const int ar  = tid >> 1;          // 0..127 row in tile
  const int ac  = (tid & 1) * 4;     // 0 or 4 col(k) in BK=8
  const int bkr = tid >> 5;          // 0..7  k-row
  const int bc  = (tid & 31) * 4;    // col in tile

  float acc[8][8];
#pragma unroll
  for (int i = 0; i < 8; ++i)
#pragma unroll
    for (int j = 0; j < 8; ++j) acc[i][j] = 0.f;

  for (int kk = 0; kk < K; kk += 8) {
    float4 av = *(const float4*)(A + (size_t)(row0 + ar) * K + kk + ac);
    float4 bv = *(const float4*)(Bm + (size_t)(kk + bkr) * N + col0 + bc);
    __syncthreads();
    As[ac + 0][ar] = av.x;
    As[ac + 1][ar] = av.y;
    As[ac + 2][ar] = av.z;
    As[ac + 3][ar] = av.w;
    *(float4*)&Bs[bkr][bc] = bv;
    __syncthreads();
#pragma unroll
    for (int k = 0; k < 8; ++k) {
      float a[8], b[8];
      *(float4*)(a)     = *(const float4*)&As[k][ty * 8];
      *(float4*)(a + 4) = *(const float4*)&As[k][ty * 8 + 4];
      *(float4*)(b)     = *(const float4*)&Bs[k][tx * 8];
      *(float4*)(b + 4) = *(const float4*)&Bs[k][tx * 8 + 4];
#pragma unroll
      for (int i = 0; i < 8; ++i)
#pragma unroll
        for (int j = 0; j < 8; ++j) acc[i][j] = fmaf(a[i], b[j], acc[i][j]);
    }
  }

  float bcol[8];
#pragma unroll
  for (int j = 0; j < 8; ++j) bcol[j] = bias[col0 + tx * 8 + j];
#pragma unroll
  for (int i = 0; i < 8; ++i) {
    const int row = row0 + ty * 8 + i;
    float o[8];
#pragma unroll
    for (int j = 0; j < 8; ++j) {
      float v = acc[i][j] + bcol[j];
      o[j] = TANH ? tanhf(v) : v;
    }
    *(float4*)(C + (size_t)row * N + col0 + tx * 8)     = *(float4*)(o);
    *(float4*)(C + (size_t)row * N + col0 + tx * 8 + 4) = *(float4*)(o + 4);
  }
}

// ------------- per-row logsumexp + gather of blank/label log-probs -------------
// logits: [chunkRows, V]; writes lp_blank[globalRow], lp_label[globalRow][Ss]
__global__ __launch_bounds__(256)
void row_lse_gather(const float* __restrict__ logits, const int* __restrict__ targets,
                    float* __restrict__ lp_blank, float* __restrict__ lp_label,
                    int rowOffset) {
  const int r = blockIdx.x;
  const int grow = rowOffset + r;              // global row = b*T + t
  const float* lrow = logits + (size_t)r * Vv;
  const int tid = threadIdx.x;

  float v[4];
  float m = NEGF;
#pragma unroll
  for (int j = 0; j < 4; ++j) {
    v[j] = lrow[tid + j * 256];
    m = fmaxf(m, v[j]);
  }
  __shared__ float wred[4];
#pragma unroll
  for (int off = 32; off > 0; off >>= 1) m = fmaxf(m, __shfl_down(m, off));
  if ((tid & 63) == 0) wred[tid >> 6] = m;
  __syncthreads();
  m = fmaxf(fmaxf(wred[0], wred[1]), fmaxf(wred[2], wred[3]));
  __syncthreads();

  float ssum = 0.f;
#pragma unroll
  for (int j = 0; j < 4; ++j) ssum += expf(v[j] - m);
#pragma unroll
  for (int off = 32; off > 0; off >>= 1) ssum += __shfl_down(ssum, off);
  if ((tid & 63) == 0) wred[tid >> 6] = ssum;
  __syncthreads();
  const float lse = m + logf(wred[0] + wred[1] + wred[2] + wred[3]);

  if (tid == 0) lp_blank[grow] = lrow[0] - lse;
  const int b = grow >> 10;                    // / Tt
  if (tid < Ss) {
    const int lab = targets[b * Ss + tid];
    lp_label[(size_t)grow * Ss + tid] = lrow[lab] - lse;
  }
}

// ------------------------------ CTC forward DP ------------------------------
__global__ __launch_bounds__(320)
void ctc_dp(const float* __restrict__ lp_blank, const float* __restrict__ lp_label,
            const int* __restrict__ targets, const int* __restrict__ lens,
            float* __restrict__ out) {
  const int b = blockIdx.x;
  const int s = threadIdx.x;
  __shared__ float alpha[2][Lext];
  __shared__ int s_tl;
  if (s == 0) s_tl = 0;
  __syncthreads();
  if (s < Ss) {
    if (targets[b * Ss + s] != 0) atomicAdd(&s_tl, 1);
  }

  const bool active = (s < Lext);
  const bool odd = (s & 1);
  const int j = (s - 1) >> 1;
  bool skip = false;
  if (active && odd && s >= 3)
    skip = (targets[b * Ss + j] != targets[b * Ss + j - 1]);

  const float* lpb = lp_blank + (size_t)b * Tt;
  const float* lpl = lp_label + (size_t)b * Tt * Ss;
  const int len = lens[b];

  if (active) {
    float a0 = NEGF;
    if (s == 0) a0 = lpb[0];
    else if (s == 1) a0 = lpl[0];
    alpha[0][s] = a0;
  }
  __syncthreads();

  int p = 0;
  float lp_cur = 0.f;
  if (active) lp_cur = odd ? lpl[(size_t)1 * Ss + j] : lpb[1];

  for (int t = 1; t < len; ++t) {
    float lp_nxt = 0.f;
    if (active && (t + 1) < len)
      lp_nxt = odd ? lpl[(size_t)(t + 1) * Ss + j] : lpb[t + 1];

    float nv = 0.f;
    if (active) {
      const float a0 = alpha[p][s];
      const float a1 = (s >= 1) ? alpha[p][s - 1] : NEGF;
      float mx = fmaxf(a0, a1);
      float r = mx + logf(expf(a0 - mx) + expf(a1 - mx));
      if (skip) {
        const float a2 = alpha[p][s - 2];
        const float m2 = fmaxf(r, a2);
        r = m2 + logf(expf(r - m2) + expf(a2 - m2));
      }
      nv = r + lp_cur;
    }
    if (active) alpha[1 - p][s] = nv;
    __syncthreads();
    p ^= 1;
    lp_cur = lp_nxt;
  }

  if (s == 0) {
    const int tl = s_tl;
    const float e1 = alpha[p][2 * tl - 1];
    const float e2 = alpha[p][2 * tl];
    const float mx = fmaxf(e1, e2);
    const float loss = -(mx + logf(expf(e1 - mx) + expf(e2 - mx)));
    out[b] = loss / (float)tl;
  }
}

// --------------------------------- launcher ---------------------------------
extern "C" void kernel_launch(void* const* d_in, const int* in_sizes, int n_in,
                              void* d_out, int out_size, void* d_ws, size_t ws_size,
                              hipStream_t stream) {
  const int*   targets = (const int*)d_in[0];
  const float* X       = (const float*)d_in[1];
  const int*   lens    = (const int*)d_in[2];
  const float* W1      = (const float*)d_in[3];
  const float* b1      = (const float*)d_in[4];
  const float* W2      = (const float*)d_in[5];
  const float* b2      = (const float*)d_in[6];
  float* out = (float*)d_out;

  const int Mtot = Bq * Tt;        // 32768
  const int CH   = 8192;           // row chunk (4 chunks)

  float* hbuf     = (float*)d_ws;                       // CH*Hh
  float* logits   = hbuf + (size_t)CH * Hh;             // CH*Vv
  float* lp_blank = logits + (size_t)CH * Vv;           // Mtot
  float* lp_label = lp_blank + Mtot;                    // Mtot*Ss

  for (int c = 0; c < Mtot / CH; ++c) {
    const float* Xc = X + (size_t)c * CH * Hh;
    gemm_bias_act<true><<<dim3(Hh / 128, CH / 128), dim3(256), 0, stream>>>(
        Xc, W1, b1, hbuf, CH, Hh, Hh);
    gemm_bias_act<false><<<dim3(Vv / 128, CH / 128), dim3(256), 0, stream>>>(
        hbuf, W2, b2, logits, CH, Vv, Hh);
    row_lse_gather<<<dim3(CH), dim3(256), 0, stream>>>(
        logits, targets, lp_blank, lp_label, c * CH);
  }
  ctc_dp<<<dim3(Bq), dim3(320), 0, stream>>>(lp_blank, lp_label, targets, lens, out);
}

// Round 2
// 752.483 us; speedup vs baseline: 1.7450x; 1.7450x over previous
//
#include <hip/hip_runtime.h>
#include <hip/hip_bf16.h>
#include <math.h>

#define Bq 32
#define Tt 1024
#define Hh 512
#define Vv 1024
#define Ss 128
#define CH 8192

typedef short bf16x8 __attribute__((ext_vector_type(8)));
typedef float f32x4 __attribute__((ext_vector_type(4)));

// ---- transpose + fp32->bf16 : out[n][k] = in[k][n], in is [K][N] ----
__global__ void transpose_cvt(const float* __restrict__ in, ushort* __restrict__ out,
                              int K, int N) {
  __shared__ float tile[32][33];
  const int k0 = blockIdx.y * 32, n0 = blockIdx.x * 32;
  const int tx = threadIdx.x, ty = threadIdx.y;
  for (int i = ty; i < 32; i += 8)
    tile[i][tx] = in[(size_t)(k0 + i) * N + n0 + tx];
  __syncthreads();
  for (int i = ty; i < 32; i += 8) {
    __hip_bfloat16 hv = __float2bfloat16(tile[tx][i]);
    out[(size_t)(n0 + i) * K + k0 + tx] = *(ushort*)&hv;
  }
}

// ---- flat fp32 -> bf16 convert (4 elems/thread) ----
__global__ __launch_bounds__(256)
void cvt_bf16(const float* __restrict__ in, ushort* __restrict__ out, int n4) {
  const int i = blockIdx.x * 256 + threadIdx.x;
  if (i >= n4) return;
  float4 v = ((const float4*)in)[i];
  __hip_bfloat16 h0 = __float2bfloat16(v.x), h1 = __float2bfloat16(v.y),
                 h2 = __float2bfloat16(v.z), h3 = __float2bfloat16(v.w);
  ushort4 u;
  u.x = *(ushort*)&h0; u.y = *(ushort*)&h1; u.z = *(ushort*)&h2; u.w = *(ushort*)&h3;
  ((ushort4*)out)[i] = u;
}

// ---- bf16 MFMA GEMM: C = act(A @ Bt^T + bias) ----
// A: [M][K] bf16 row-major; Bt: [N][K] bf16 row-major (pre-transposed weights)
template<bool TANH, bool OUTBF16>
__global__ __launch_bounds__(256)
void gemm_mfma(const ushort* __restrict__ A, const ushort* __restrict__ Bt,
               const float* __restrict__ bias, void* __restrict__ Cout,
               int M, int N, int K) {
  __shared__ ushort As[128 * 64];
  __shared__ ushort Bs[128 * 64];
  const int tid = threadIdx.x;
  const int lane = tid & 63, wave = tid >> 6;
  const int wm = wave >> 1, wn = wave & 1;
  const int q = lane >> 4, r16 = lane & 15;
  const int row0 = blockIdx.y * 128, col0 = blockIdx.x * 128;
  const int lrow = lane >> 3;        // row within 8-row segment
  const int lcol = (lane & 7) * 8;   // elem col within 64

  f32x4 acc[4][4];
#pragma unroll
  for (int i = 0; i < 4; ++i)
#pragma unroll
    for (int j = 0; j < 4; ++j) acc[i][j] = (f32x4){0.f, 0.f, 0.f, 0.f};

  for (int kk = 0; kk < K; kk += 64) {
    __syncthreads();
#pragma unroll
    for (int i = 0; i < 4; ++i) {
      const int seg = wave * 4 + i;     // 16 segments of 8 rows
      const int r = seg * 8 + lrow;
      __builtin_amdgcn_global_load_lds(
          (const __attribute__((address_space(1))) void*)(A + (size_t)(row0 + r) * K + kk + lcol),
          (__attribute__((address_space(3))) void*)(As + seg * 512),
          16, 0, 0);
      __builtin_amdgcn_global_load_lds(
          (const __attribute__((address_space(1))) void*)(Bt + (size_t)(col0 + r) * K + kk + lcol),
          (__attribute__((address_space(3))) void*)(Bs + seg * 512),
          16, 0, 0);
    }
    __syncthreads();
#pragma unroll
    for (int ks = 0; ks < 64; ks += 32) {
      bf16x8 af[4], bfr[4];
#pragma unroll
      for (int mi = 0; mi < 4; ++mi)
        af[mi] = *(const bf16x8*)(As + ((wm * 64 + mi * 16 + r16) << 6) + ks + q * 8);
#pragma unroll
      for (int ni = 0; ni < 4; ++ni)
        bfr[ni] = *(const bf16x8*)(Bs + ((wn * 64 + ni * 16 + r16) << 6) + ks + q * 8);
#pragma unroll
      for (int mi = 0; mi < 4; ++mi)
#pragma unroll
        for (int ni = 0; ni < 4; ++ni)
          acc[mi][ni] = __builtin_amdgcn_mfma_f32_16x16x32_bf16(af[mi], bfr[ni], acc[mi][ni], 0, 0, 0);
    }
  }
  // epilogue: C/D layout col=lane&15, row=(lane>>4)*4+reg
#pragma unroll
  for (int ni = 0; ni < 4; ++ni) {
    const int col = col0 + wn * 64 + ni * 16 + r16;
    const float bc = bias[col];
#pragma unroll
    for (int mi = 0; mi < 4; ++mi) {
#pragma unroll
      for (int r = 0; r < 4; ++r) {
        const int row = row0 + wm * 64 + mi * 16 + q * 4 + r;
        float v = acc[mi][ni][r] + bc;
        if (TANH) v = tanhf(v);
        if (OUTBF16) {
          __hip_bfloat16 hv = __float2bfloat16(v);
          ((ushort*)Cout)[(size_t)row * N + col] = *(ushort*)&hv;
        } else {
          ((float*)Cout)[(size_t)row * N + col] = v;
        }
      }
    }
  }
}

// ---- per-row softmax: writes PROBABILITIES of blank + the 128 labels ----
__global__ __launch_bounds__(256)
void row_lse_gather(const float* __restrict__ logits, const int* __restrict__ targets,
                    float* __restrict__ pb, float* __restrict__ pl, int rowOffset) {
  const int r = blockIdx.x;
  const int grow = rowOffset + r;          // global row = b*T + t
  const float* lrow = logits + (size_t)r * Vv;
  const int tid = threadIdx.x;

  float v[4];
  float m = -1e30f;
#pragma unroll
  for (int j = 0; j < 4; ++j) {
    v[j] = lrow[tid + j * 256];
    m = fmaxf(m, v[j]);
  }
  __shared__ float wred[4];
#pragma unroll
  for (int off = 32; off > 0; off >>= 1) m = fmaxf(m, __shfl_down(m, off));
  if ((tid & 63) == 0) wred[tid >> 6] = m;
  __syncthreads();
  m = fmaxf(fmaxf(wred[0], wred[1]), fmaxf(wred[2], wred[3]));
  __syncthreads();

  float ssum = 0.f;
#pragma unroll
  for (int j = 0; j < 4; ++j) ssum += expf(v[j] - m);
#pragma unroll
  for (int off = 32; off > 0; off >>= 1) ssum += __shfl_down(ssum, off);
  if ((tid & 63) == 0) wred[tid >> 6] = ssum;
  __syncthreads();
  const float lse = m + logf(wred[0] + wred[1] + wred[2] + wred[3]);

  if (tid == 0) pb[grow] = expf(lrow[0] - lse);
  const int b = grow >> 10;
  if (tid < Ss) {
    const int lab = targets[b * Ss + tid];
    pl[(size_t)grow * Ss + tid] = expf(lrow[lab] - lse);
  }
}

// ---- CTC forward DP, linear domain with exact pow2 rescaling ----
// one wave per example; lane l owns states 5l..5l+4 in registers
__global__ __launch_bounds__(64)
void ctc_dp(const float* __restrict__ pb, const float* __restrict__ pl,
            const int* __restrict__ tgt, const int* __restrict__ lens,
            float* __restrict__ out) {
  const int b = blockIdx.x, l = threadIdx.x;
  const float* pbr = pb + (size_t)b * Tt;
  const float* plr = pl + (size_t)b * Tt * Ss;
  const int* tg = tgt + b * Ss;

  float skipf[5];
  int jj[5];
  bool odd[5], valid[5];
#pragma unroll
  for (int i = 0; i < 5; ++i) {
    const int s = 5 * l + i;
    valid[i] = (s < 2 * Ss + 1);
    odd[i] = (s & 1);
    jj[i] = (s - 1) >> 1;
    bool sk = false;
    if (valid[i] && odd[i] && s >= 3) sk = (tg[jj[i]] != tg[jj[i] - 1]);
    skipf[i] = sk ? 1.f : 0.f;
  }

  float a[5];
#pragma unroll
  for (int i = 0; i < 5; ++i) a[i] = 0.f;
  if (l == 0) { a[0] = pbr[0]; a[1] = plr[0]; }

  const int len = lens[b];
  float p[5];
#pragma unroll
  for (int i = 0; i < 5; ++i)
    p[i] = valid[i] ? (odd[i] ? plr[Ss + jj[i]] : pbr[1]) : 0.f;

  int E = 0;
  for (int t = 1; t < len; ++t) {
    const int tn = (t + 1 < len) ? (t + 1) : t;
    float pn[5];
#pragma unroll
    for (int i = 0; i < 5; ++i)
      pn[i] = valid[i] ? (odd[i] ? plr[(size_t)tn * Ss + jj[i]] : pbr[tn]) : 0.f;

    const float prev1 = __shfl(a[4], (l + 63) & 63);  // alpha[5l-1]; lane0 -> lane63 (always 0)
    const float prev2 = __shfl(a[3], (l + 63) & 63);  // alpha[5l-2]
    const float n0 = (a[0] + prev1 + skipf[0] * prev2) * p[0];
    const float n1 = (a[1] + a[0] + skipf[1] * prev1) * p[1];
    const float n2 = (a[2] + a[1] + skipf[2] * a[0]) * p[2];
    const float n3 = (a[3] + a[2] + skipf[3] * a[1]) * p[3];
    const float n4 = (a[4] + a[3] + skipf[4] * a[2]) * p[4];
    a[0] = n0; a[1] = n1; a[2] = n2; a[3] = n3; a[4] = n4;
#pragma unroll
    for (int i = 0; i < 5; ++i) p[i] = pn[i];

    if ((t & 7) == 0) {  // exact power-of-2 renorm: keep max near 2^60
      float m = fmaxf(fmaxf(fmaxf(a[0], a[1]), fmaxf(a[2], a[3])), a[4]);
#pragma unroll
      for (int off = 1; off < 64; off <<= 1) m = fmaxf(m, __shfl_xor(m, off));
      const int e = (int)((__float_as_uint(m) >> 23) & 255) - 127;
      int sh = 60 - e;
      if (sh > 120) sh = 120;
      const float scale = __uint_as_float((unsigned)(127 + sh) << 23);
      E -= sh;
#pragma unroll
      for (int i = 0; i < 5; ++i) a[i] *= scale;
    }
  }

  const int tl = __popcll(__ballot(tg[l] != 0)) + __popcll(__ballot(tg[64 + l] != 0));
  const int s1 = 2 * tl - 1, s2 = 2 * tl;
  float v = 0.f;
#pragma unroll
  for (int i = 0; i < 5; ++i) {
    const int s = 5 * l + i;
    if (s == s1 || s == s2) v += a[i];
  }
#pragma unroll
  for (int off = 1; off < 64; off <<= 1) v += __shfl_xor(v, off);
  if (l == 0)
    out[b] = -((log2f(v) + (float)E) * 0.6931471805599453f) / (float)tl;
}

// --------------------------------- launcher ---------------------------------
extern "C" void kernel_launch(void* const* d_in, const int* in_sizes, int n_in,
                              void* d_out, int out_size, void* d_ws, size_t ws_size,
                              hipStream_t stream) {
  const int*   targets = (const int*)d_in[0];
  const float* X       = (const float*)d_in[1];
  const int*   lens    = (const int*)d_in[2];
  const float* W1      = (const float*)d_in[3];
  const float* b1      = (const float*)d_in[4];
  const float* W2      = (const float*)d_in[5];
  const float* b2      = (const float*)d_in[6];
  float* out = (float*)d_out;

  // workspace layout (Xc aliases logits: disjoint live ranges)
  float*  logits = (float*)d_ws;                         // CH*Vv fp32   (33.55 MB)
  ushort* Xc     = (ushort*)d_ws;                        // CH*Hh bf16   (aliased)
  ushort* h      = (ushort*)(logits + (size_t)CH * Vv);  // CH*Hh bf16   (8.39 MB)
  ushort* W1T    = h + (size_t)CH * Hh;                  // Hh*Hh bf16   (0.52 MB)
  ushort* W2T    = W1T + (size_t)Hh * Hh;                // Vv*Hh bf16   (1.05 MB)
  float*  pb     = (float*)(W2T + (size_t)Hh * Vv);      // B*T fp32     (0.13 MB)
  float*  pl     = pb + (size_t)Bq * Tt;                 // B*T*S fp32   (16.78 MB)

  transpose_cvt<<<dim3(Hh / 32, Hh / 32), dim3(32, 8), 0, stream>>>(W1, W1T, Hh, Hh);
  transpose_cvt<<<dim3(Vv / 32, Hh / 32), dim3(32, 8), 0, stream>>>(W2, W2T, Hh, Vv);

  for (int c = 0; c < (Bq * Tt) / CH; ++c) {
    cvt_bf16<<<dim3((CH * Hh / 4) / 256), dim3(256), 0, stream>>>(
        X + (size_t)c * CH * Hh, Xc, CH * Hh / 4);
    gemm_mfma<true, true><<<dim3(Hh / 128, CH / 128), dim3(256), 0, stream>>>(
        Xc, W1T, b1, h, CH, Hh, Hh);
    gemm_mfma<false, false><<<dim3(Vv / 128, CH / 128), dim3(256), 0, stream>>>(
        h, W2T, b2, logits, CH, Vv, Hh);
    row_lse_gather<<<dim3(CH), dim3(256), 0, stream>>>(logits, targets, pb, pl, c * CH);
  }
  ctc_dp<<<dim3(Bq), dim3(64), 0, stream>>>(pb, pl, targets, lens, out);
}

// Round 3
// 562.101 us; speedup vs baseline: 2.3361x; 1.3387x over previous
//
#include <hip/hip_runtime.h>
#include <hip/hip_bf16.h>
#include <math.h>

#define Bq 32
#define Tt 1024
#define Hh 512
#define Vv 1024
#define Ss 128
#define CH 8192

typedef short bf16x8 __attribute__((ext_vector_type(8)));
typedef float f32x4 __attribute__((ext_vector_type(4)));

// ---- transpose + fp32->bf16 : out[n][k] = in[k][n], in is [K][N] ----
__global__ void transpose_cvt(const float* __restrict__ in, ushort* __restrict__ out,
                              int K, int N) {
  __shared__ float tile[32][33];
  const int k0 = blockIdx.y * 32, n0 = blockIdx.x * 32;
  const int tx = threadIdx.x, ty = threadIdx.y;
  for (int i = ty; i < 32; i += 8)
    tile[i][tx] = in[(size_t)(k0 + i) * N + n0 + tx];
  __syncthreads();
  for (int i = ty; i < 32; i += 8) {
    __hip_bfloat16 hv = __float2bfloat16(tile[tx][i]);
    out[(size_t)(n0 + i) * K + k0 + tx] = *(ushort*)&hv;
  }
}

// ---- flat fp32 -> bf16 convert (4 elems/thread) ----
__global__ __launch_bounds__(256)
void cvt_bf16(const float* __restrict__ in, ushort* __restrict__ out, int n4) {
  const int i = blockIdx.x * 256 + threadIdx.x;
  if (i >= n4) return;
  float4 v = ((const float4*)in)[i];
  __hip_bfloat16 h0 = __float2bfloat16(v.x), h1 = __float2bfloat16(v.y),
                 h2 = __float2bfloat16(v.z), h3 = __float2bfloat16(v.w);
  ushort4 u;
  u.x = *(ushort*)&h0; u.y = *(ushort*)&h1; u.z = *(ushort*)&h2; u.w = *(ushort*)&h3;
  ((ushort4*)out)[i] = u;
}

// ---- bf16 MFMA GEMM: C = act(A @ Bt^T + bias) ----
// A: [M][K] bf16 row-major; Bt: [N][K] bf16 row-major (pre-transposed weights)
template<bool TANH, bool OUTBF16>
__global__ __launch_bounds__(256)
void gemm_mfma(const ushort* __restrict__ A, const ushort* __restrict__ Bt,
               const float* __restrict__ bias, void* __restrict__ Cout,
               int M, int N, int K) {
  __shared__ ushort As[128 * 64];
  __shared__ ushort Bs[128 * 64];
  const int tid = threadIdx.x;
  const int lane = tid & 63, wave = tid >> 6;
  const int wm = wave >> 1, wn = wave & 1;
  const int q = lane >> 4, r16 = lane & 15;
  const int row0 = blockIdx.y * 128, col0 = blockIdx.x * 128;
  const int lrow = lane >> 3;        // row within 8-row segment
  const int lcol = (lane & 7) * 8;   // elem col within 64

  f32x4 acc[4][4];
#pragma unroll
  for (int i = 0; i < 4; ++i)
#pragma unroll
    for (int j = 0; j < 4; ++j) acc[i][j] = (f32x4){0.f, 0.f, 0.f, 0.f};

  for (int kk = 0; kk < K; kk += 64) {
    __syncthreads();
#pragma unroll
    for (int i = 0; i < 4; ++i) {
      const int seg = wave * 4 + i;     // 16 segments of 8 rows
      const int r = seg * 8 + lrow;
      __builtin_amdgcn_global_load_lds(
          (const __attribute__((address_space(1))) void*)(A + (size_t)(row0 + r) * K + kk + lcol),
          (__attribute__((address_space(3))) void*)(As + seg * 512),
          16, 0, 0);
      __builtin_amdgcn_global_load_lds(
          (const __attribute__((address_space(1))) void*)(Bt + (size_t)(col0 + r) * K + kk + lcol),
          (__attribute__((address_space(3))) void*)(Bs + seg * 512),
          16, 0, 0);
    }
    __syncthreads();
#pragma unroll
    for (int ks = 0; ks < 64; ks += 32) {
      bf16x8 af[4], bfr[4];
#pragma unroll
      for (int mi = 0; mi < 4; ++mi)
        af[mi] = *(const bf16x8*)(As + ((wm * 64 + mi * 16 + r16) << 6) + ks + q * 8);
#pragma unroll
      for (int ni = 0; ni < 4; ++ni)
        bfr[ni] = *(const bf16x8*)(Bs + ((wn * 64 + ni * 16 + r16) << 6) + ks + q * 8);
#pragma unroll
      for (int mi = 0; mi < 4; ++mi)
#pragma unroll
        for (int ni = 0; ni < 4; ++ni)
          acc[mi][ni] = __builtin_amdgcn_mfma_f32_16x16x32_bf16(af[mi], bfr[ni], acc[mi][ni], 0, 0, 0);
    }
  }
  // epilogue: C/D layout col=lane&15, row=(lane>>4)*4+reg
#pragma unroll
  for (int ni = 0; ni < 4; ++ni) {
    const int col = col0 + wn * 64 + ni * 16 + r16;
    const float bc = bias[col];
#pragma unroll
    for (int mi = 0; mi < 4; ++mi) {
#pragma unroll
      for (int r = 0; r < 4; ++r) {
        const int row = row0 + wm * 64 + mi * 16 + q * 4 + r;
        float v = acc[mi][ni][r] + bc;
        if (TANH) v = tanhf(v);
        if (OUTBF16) {
          __hip_bfloat16 hv = __float2bfloat16(v);
          ((ushort*)Cout)[(size_t)row * N + col] = *(ushort*)&hv;
        } else {
          ((float*)Cout)[(size_t)row * N + col] = v;
        }
      }
    }
  }
}

// ---- per-row softmax: writes PROBABILITIES of blank + the 128 labels ----
__global__ __launch_bounds__(256)
void row_lse_gather(const float* __restrict__ logits, const int* __restrict__ targets,
                    float* __restrict__ pb, float* __restrict__ pl, int rowOffset) {
  const int r = blockIdx.x;
  const int grow = rowOffset + r;          // global row = b*T + t
  const float* lrow = logits + (size_t)r * Vv;
  const int tid = threadIdx.x;

  float v[4];
  float m = -1e30f;
#pragma unroll
  for (int j = 0; j < 4; ++j) {
    v[j] = lrow[tid + j * 256];
    m = fmaxf(m, v[j]);
  }
  __shared__ float wred[4];
#pragma unroll
  for (int off = 32; off > 0; off >>= 1) m = fmaxf(m, __shfl_down(m, off));
  if ((tid & 63) == 0) wred[tid >> 6] = m;
  __syncthreads();
  m = fmaxf(fmaxf(wred[0], wred[1]), fmaxf(wred[2], wred[3]));
  __syncthreads();

  float ssum = 0.f;
#pragma unroll
  for (int j = 0; j < 4; ++j) ssum += expf(v[j] - m);
#pragma unroll
  for (int off = 32; off > 0; off >>= 1) ssum += __shfl_down(ssum, off);
  if ((tid & 63) == 0) wred[tid >> 6] = ssum;
  __syncthreads();
  const float lse = m + logf(wred[0] + wred[1] + wred[2] + wred[3]);

  if (tid == 0) pb[grow] = expf(lrow[0] - lse);
  const int b = grow >> 10;
  if (tid < Ss) {
    const int lab = targets[b * Ss + tid];
    pl[(size_t)grow * Ss + tid] = expf(lrow[lab] - lse);
  }
}

// ---- CTC forward DP, linear domain with exact pow2 rescaling ----
// one wave per example; lane l owns states 5l..5l+4 in registers.
// pl is staged 64 t-steps at a time into double-buffered LDS via
// global_load_lds (contiguous 32 KB per chunk), prefetched one chunk ahead
// so the per-step chain never touches global latency.
__global__ __launch_bounds__(64)
void ctc_dp(const float* __restrict__ pb, const float* __restrict__ pl,
            const int* __restrict__ tgt, const int* __restrict__ lens,
            float* __restrict__ out) {
  __shared__ float pl_lds[2][64 * 128];   // 2 x 32 KB
  __shared__ float pb_lds[2][64];
  const int b = blockIdx.x, l = threadIdx.x;
  const float* pbr = pb + (size_t)b * Tt;
  const float* plr = pl + (size_t)b * Tt * Ss;
  const int* tg = tgt + b * Ss;

  float skipf[5];
  int jj[5];
  bool odd[5], valid[5];
#pragma unroll
  for (int i = 0; i < 5; ++i) {
    const int s = 5 * l + i;
    valid[i] = (s < 2 * Ss + 1);
    odd[i] = (s & 1);
    jj[i] = (s - 1) >> 1;
    bool sk = false;
    if (valid[i] && odd[i] && s >= 3) sk = (tg[jj[i]] != tg[jj[i] - 1]);
    skipf[i] = sk ? 1.f : 0.f;
  }

  auto stage = [&](int c, int d) {
    const float* srcp = plr + (size_t)c * 64 * 128;
#pragma unroll
    for (int i = 0; i < 32; ++i)
      __builtin_amdgcn_global_load_lds(
          (const __attribute__((address_space(1))) void*)(srcp + i * 256 + l * 4),
          (__attribute__((address_space(3))) void*)(&pl_lds[d][i * 256]),
          16, 0, 0);
    __builtin_amdgcn_global_load_lds(
        (const __attribute__((address_space(1))) void*)(pbr + c * 64 + l),
        (__attribute__((address_space(3))) void*)(&pb_lds[d][0]),
        4, 0, 0);
  };

  stage(0, 0);
  __syncthreads();   // drain vmcnt for chunk 0

  float a[5];
#pragma unroll
  for (int i = 0; i < 5; ++i) a[i] = 0.f;
  if (l == 0) { a[0] = pb_lds[0][0]; a[1] = pl_lds[0][0]; }

  const int len = lens[b];
  int E = 0;

  for (int c = 0; c < Tt / 64; ++c) {
    const int d = c & 1;
    if (c + 1 < Tt / 64) stage(c + 1, 1 - d);   // prefetch next chunk (fire-and-forget)

    const int t_lo = (c == 0) ? 1 : c * 64;
    const int t_hi = min((c + 1) * 64, len);

    if (t_lo < t_hi) {
      // 1-step software pipeline of the LDS p-reads
      float p[5];
      {
        const int st = t_lo - c * 64;
        const float pbv = pb_lds[d][st];
#pragma unroll
        for (int i = 0; i < 5; ++i)
          p[i] = valid[i] ? (odd[i] ? pl_lds[d][st * 128 + jj[i]] : pbv) : 0.f;
      }
      for (int t = t_lo; t < t_hi; ++t) {
        const int stn = min(t + 1 - c * 64, 63);   // next step (clamped; unused past t_hi-1)
        float pn[5];
        const float pbvn = pb_lds[d][stn];
#pragma unroll
        for (int i = 0; i < 5; ++i)
          pn[i] = valid[i] ? (odd[i] ? pl_lds[d][stn * 128 + jj[i]] : pbvn) : 0.f;

        const float prev1 = __shfl(a[4], (l + 63) & 63);  // alpha[5l-1] (lane0 wraps to always-0)
        const float prev2 = __shfl(a[3], (l + 63) & 63);  // alpha[5l-2]
        const float n0 = (a[0] + prev1 + skipf[0] * prev2) * p[0];
        const float n1 = (a[1] + a[0] + skipf[1] * prev1) * p[1];
        const float n2 = (a[2] + a[1] + skipf[2] * a[0]) * p[2];
        const float n3 = (a[3] + a[2] + skipf[3] * a[1]) * p[3];
        const float n4 = (a[4] + a[3] + skipf[4] * a[2]) * p[4];
        a[0] = n0; a[1] = n1; a[2] = n2; a[3] = n3; a[4] = n4;
#pragma unroll
        for (int i = 0; i < 5; ++i) p[i] = pn[i];

        if ((t & 7) == 0) {  // exact power-of-2 renorm: keep max near 2^60
          float m = fmaxf(fmaxf(fmaxf(a[0], a[1]), fmaxf(a[2], a[3])), a[4]);
#pragma unroll
          for (int off = 1; off < 64; off <<= 1) m = fmaxf(m, __shfl_xor(m, off));
          const int e = (int)((__float_as_uint(m) >> 23) & 255) - 127;
          int sh = 60 - e;
          if (sh > 120) sh = 120;
          const float scale = __uint_as_float((unsigned)(127 + sh) << 23);
          E -= sh;
#pragma unroll
          for (int i = 0; i < 5; ++i) a[i] *= scale;
        }
      }
    }
    __syncthreads();   // drain prefetch before switching buffers
  }

  const int tl = __popcll(__ballot(tg[l] != 0)) + __popcll(__ballot(tg[64 + l] != 0));
  const int s1 = 2 * tl - 1, s2 = 2 * tl;
  float v = 0.f;
#pragma unroll
  for (int i = 0; i < 5; ++i) {
    const int s = 5 * l + i;
    if (s == s1 || s == s2) v += a[i];
  }
#pragma unroll
  for (int off = 1; off < 64; off <<= 1) v += __shfl_xor(v, off);
  if (l == 0)
    out[b] = -((log2f(v) + (float)E) * 0.6931471805599453f) / (float)tl;
}

// --------------------------------- launcher ---------------------------------
extern "C" void kernel_launch(void* const* d_in, const int* in_sizes, int n_in,
                              void* d_out, int out_size, void* d_ws, size_t ws_size,
                              hipStream_t stream) {
  const int*   targets = (const int*)d_in[0];
  const float* X       = (const float*)d_in[1];
  const int*   lens    = (const int*)d_in[2];
  const float* W1      = (const float*)d_in[3];
  const float* b1      = (const float*)d_in[4];
  const float* W2      = (const float*)d_in[5];
  const float* b2      = (const float*)d_in[6];
  float* out = (float*)d_out;

  // workspace layout (Xc aliases logits: disjoint live ranges)
  float*  logits = (float*)d_ws;                         // CH*Vv fp32   (33.55 MB)
  ushort* Xc     = (ushort*)d_ws;                        // CH*Hh bf16   (aliased)
  ushort* h      = (ushort*)(logits + (size_t)CH * Vv);  // CH*Hh bf16   (8.39 MB)
  ushort* W1T    = h + (size_t)CH * Hh;                  // Hh*Hh bf16   (0.52 MB)
  ushort* W2T    = W1T + (size_t)Hh * Hh;                // Vv*Hh bf16   (1.05 MB)
  float*  pb     = (float*)(W2T + (size_t)Hh * Vv);      // B*T fp32     (0.13 MB)
  float*  pl     = pb + (size_t)Bq * Tt;                 // B*T*S fp32   (16.78 MB)

  transpose_cvt<<<dim3(Hh / 32, Hh / 32), dim3(32, 8), 0, stream>>>(W1, W1T, Hh, Hh);
  transpose_cvt<<<dim3(Vv / 32, Hh / 32), dim3(32, 8), 0, stream>>>(W2, W2T, Hh, Vv);

  for (int c = 0; c < (Bq * Tt) / CH; ++c) {
    cvt_bf16<<<dim3((CH * Hh / 4) / 256), dim3(256), 0, stream>>>(
        X + (size_t)c * CH * Hh, Xc, CH * Hh / 4);
    gemm_mfma<true, true><<<dim3(Hh / 128, CH / 128), dim3(256), 0, stream>>>(
        Xc, W1T, b1, h, CH, Hh, Hh);
    gemm_mfma<false, false><<<dim3(Vv / 128, CH / 128), dim3(256), 0, stream>>>(
        h, W2T, b2, logits, CH, Vv, Hh);
    row_lse_gather<<<dim3(CH), dim3(256), 0, stream>>>(logits, targets, pb, pl, c * CH);
  }
  ctc_dp<<<dim3(Bq), dim3(64), 0, stream>>>(pb, pl, targets, lens, out);
}

// Round 4
// 397.637 us; speedup vs baseline: 3.3023x; 1.4136x over previous
//
#include <hip/hip_runtime.h>
#include <hip/hip_bf16.h>
#include <math.h>

#define Bq 32
#define Tt 1024
#define Hh 512
#define Vv 1024
#define Ss 128
#define CH 8192

typedef short bf16x8 __attribute__((ext_vector_type(8)));
typedef float f32x4 __attribute__((ext_vector_type(4)));

// ---- transpose + fp32->bf16 : out[n][k] = in[k][n], in is [K][N] ----
__global__ void transpose_cvt(const float* __restrict__ in, ushort* __restrict__ out,
                              int K, int N) {
  __shared__ float tile[32][33];
  const int k0 = blockIdx.y * 32, n0 = blockIdx.x * 32;
  const int tx = threadIdx.x, ty = threadIdx.y;
  for (int i = ty; i < 32; i += 8)
    tile[i][tx] = in[(size_t)(k0 + i) * N + n0 + tx];
  __syncthreads();
  for (int i = ty; i < 32; i += 8) {
    __hip_bfloat16 hv = __float2bfloat16(tile[tx][i]);
    out[(size_t)(n0 + i) * K + k0 + tx] = *(ushort*)&hv;
  }
}

// ---- flat fp32 -> bf16 convert (4 elems/thread) ----
__global__ __launch_bounds__(256)
void cvt_bf16(const float* __restrict__ in, ushort* __restrict__ out, int n4) {
  const int i = blockIdx.x * 256 + threadIdx.x;
  if (i >= n4) return;
  float4 v = ((const float4*)in)[i];
  __hip_bfloat16 h0 = __float2bfloat16(v.x), h1 = __float2bfloat16(v.y),
                 h2 = __float2bfloat16(v.z), h3 = __float2bfloat16(v.w);
  ushort4 u;
  u.x = *(ushort*)&h0; u.y = *(ushort*)&h1; u.z = *(ushort*)&h2; u.w = *(ushort*)&h3;
  ((ushort4*)out)[i] = u;
}

// ---- bf16 MFMA GEMM: C = act(A @ Bt^T + bias) ----
template<bool TANH, bool OUTBF16>
__global__ __launch_bounds__(256)
void gemm_mfma(const ushort* __restrict__ A, const ushort* __restrict__ Bt,
               const float* __restrict__ bias, void* __restrict__ Cout,
               int M, int N, int K) {
  __shared__ ushort As[128 * 64];
  __shared__ ushort Bs[128 * 64];
  const int tid = threadIdx.x;
  const int lane = tid & 63, wave = tid >> 6;
  const int wm = wave >> 1, wn = wave & 1;
  const int q = lane >> 4, r16 = lane & 15;
  const int row0 = blockIdx.y * 128, col0 = blockIdx.x * 128;
  const int lrow = lane >> 3;
  const int lcol = (lane & 7) * 8;

  f32x4 acc[4][4];
#pragma unroll
  for (int i = 0; i < 4; ++i)
#pragma unroll
    for (int j = 0; j < 4; ++j) acc[i][j] = (f32x4){0.f, 0.f, 0.f, 0.f};

  for (int kk = 0; kk < K; kk += 64) {
    __syncthreads();
#pragma unroll
    for (int i = 0; i < 4; ++i) {
      const int seg = wave * 4 + i;
      const int r = seg * 8 + lrow;
      __builtin_amdgcn_global_load_lds(
          (const __attribute__((address_space(1))) void*)(A + (size_t)(row0 + r) * K + kk + lcol),
          (__attribute__((address_space(3))) void*)(As + seg * 512),
          16, 0, 0);
      __builtin_amdgcn_global_load_lds(
          (const __attribute__((address_space(1))) void*)(Bt + (size_t)(col0 + r) * K + kk + lcol),
          (__attribute__((address_space(3))) void*)(Bs + seg * 512),
          16, 0, 0);
    }
    __syncthreads();
#pragma unroll
    for (int ks = 0; ks < 64; ks += 32) {
      bf16x8 af[4], bfr[4];
#pragma unroll
      for (int mi = 0; mi < 4; ++mi)
        af[mi] = *(const bf16x8*)(As + ((wm * 64 + mi * 16 + r16) << 6) + ks + q * 8);
#pragma unroll
      for (int ni = 0; ni < 4; ++ni)
        bfr[ni] = *(const bf16x8*)(Bs + ((wn * 64 + ni * 16 + r16) << 6) + ks + q * 8);
#pragma unroll
      for (int mi = 0; mi < 4; ++mi)
#pragma unroll
        for (int ni = 0; ni < 4; ++ni)
          acc[mi][ni] = __builtin_amdgcn_mfma_f32_16x16x32_bf16(af[mi], bfr[ni], acc[mi][ni], 0, 0, 0);
    }
  }
#pragma unroll
  for (int ni = 0; ni < 4; ++ni) {
    const int col = col0 + wn * 64 + ni * 16 + r16;
    const float bc = bias[col];
#pragma unroll
    for (int mi = 0; mi < 4; ++mi) {
#pragma unroll
      for (int r = 0; r < 4; ++r) {
        const int row = row0 + wm * 64 + mi * 16 + q * 4 + r;
        float v = acc[mi][ni][r] + bc;
        if (TANH) v = tanhf(v);
        if (OUTBF16) {
          __hip_bfloat16 hv = __float2bfloat16(v);
          ((ushort*)Cout)[(size_t)row * N + col] = *(ushort*)&hv;
        } else {
          ((float*)Cout)[(size_t)row * N + col] = v;
        }
      }
    }
  }
}

// ---- per-row softmax: writes bf16 PROBABILITIES, split blank/labels ----
__global__ __launch_bounds__(256)
void row_lse_gather(const float* __restrict__ logits, const int* __restrict__ targets,
                    ushort* __restrict__ pBlank, ushort* __restrict__ pOdd, int rowOffset) {
  const int r = blockIdx.x;
  const int grow = rowOffset + r;
  const float* lrow = logits + (size_t)r * Vv;
  const int tid = threadIdx.x;

  float v[4];
  float m = -1e30f;
#pragma unroll
  for (int j = 0; j < 4; ++j) {
    v[j] = lrow[tid + j * 256];
    m = fmaxf(m, v[j]);
  }
  __shared__ float wred[4];
#pragma unroll
  for (int off = 32; off > 0; off >>= 1) m = fmaxf(m, __shfl_down(m, off));
  if ((tid & 63) == 0) wred[tid >> 6] = m;
  __syncthreads();
  m = fmaxf(fmaxf(wred[0], wred[1]), fmaxf(wred[2], wred[3]));
  __syncthreads();

  float ssum = 0.f;
#pragma unroll
  for (int j = 0; j < 4; ++j) ssum += expf(v[j] - m);
#pragma unroll
  for (int off = 32; off > 0; off >>= 1) ssum += __shfl_down(ssum, off);
  if ((tid & 63) == 0) wred[tid >> 6] = ssum;
  __syncthreads();
  const float lse = m + logf(wred[0] + wred[1] + wred[2] + wred[3]);

  if (tid == 0) {
    __hip_bfloat16 hv = __float2bfloat16(expf(lrow[0] - lse));
    pBlank[grow] = *(ushort*)&hv;
  }
  const int b = grow >> 10;
  if (tid < Ss) {
    const int lab = targets[b * Ss + tid];
    __hip_bfloat16 hv = __float2bfloat16(expf(lrow[lab] - lse));
    pOdd[(size_t)grow * Ss + tid] = *(ushort*)&hv;
  }
}

// ---- DPP helpers ----
__device__ __forceinline__ float dpp_wshr1(float x) {
  // whole-wave shift toward higher lanes by 1; lane 0 gets 0
  return __int_as_float(__builtin_amdgcn_update_dpp(
      0, __float_as_int(x), 0x138, 0xf, 0xf, true));
}
__device__ __forceinline__ float dpp_wave_max(float m) {
  m = fmaxf(m, __int_as_float(__builtin_amdgcn_update_dpp(0, __float_as_int(m), 0x111, 0xf, 0xf, true)));
  m = fmaxf(m, __int_as_float(__builtin_amdgcn_update_dpp(0, __float_as_int(m), 0x112, 0xf, 0xf, true)));
  m = fmaxf(m, __int_as_float(__builtin_amdgcn_update_dpp(0, __float_as_int(m), 0x114, 0xf, 0xf, true)));
  m = fmaxf(m, __int_as_float(__builtin_amdgcn_update_dpp(0, __float_as_int(m), 0x118, 0xf, 0xf, true)));
  m = fmaxf(m, __int_as_float(__builtin_amdgcn_update_dpp(__float_as_int(m), __float_as_int(m), 0x142, 0xf, 0xf, false)));
  m = fmaxf(m, __int_as_float(__builtin_amdgcn_update_dpp(__float_as_int(m), __float_as_int(m), 0x143, 0xf, 0xf, false)));
  return __int_as_float(__builtin_amdgcn_readlane(__float_as_int(m), 63));
}

// ---- CTC forward DP: linear domain, 4 states/lane (+state 256 on lane 63),
// DPP halo, bf16 probs staged in double-buffered LDS, 4-deep read pipeline ----
__global__ __launch_bounds__(64)
void ctc_dp(const ushort* __restrict__ pOddG, const ushort* __restrict__ pBlankG,
            const int* __restrict__ tgt, const int* __restrict__ lens,
            float* __restrict__ out) {
  __shared__ ushort pO[2][64 * 128];   // 2 x 16 KB  (64 steps x 128 labels)
  __shared__ ushort pBl[2][128];       // 2 x 256 B  (64 steps + pad)
  const int b = blockIdx.x, l = threadIdx.x;
  const ushort* pObase = pOddG + (size_t)b * Tt * Ss;
  const ushort* pBbase = pBlankG + (size_t)b * Tt;
  const int* tg = tgt + b * Ss;
  const int len = lens[b];

  // skip flags for this lane's odd states s=4l+1 (j=2l) and s=4l+3 (j=2l+1)
  float sk1 = 0.f, sk3 = 0.f;
  if (l >= 1) sk1 = (tg[2 * l] != tg[2 * l - 1]) ? 1.f : 0.f;
  sk3 = (tg[2 * l + 1] != tg[2 * l]) ? 1.f : 0.f;

  auto stage = [&](int c, int d) {
    const ushort* src = pObase + (size_t)c * 64 * 128;
#pragma unroll
    for (int i = 0; i < 16; ++i)
      __builtin_amdgcn_global_load_lds(
          (const __attribute__((address_space(1))) void*)(src + (i * 64 + l) * 8),
          (__attribute__((address_space(3))) void*)(&pO[d][i * 512]),
          16, 0, 0);
    __builtin_amdgcn_global_load_lds(
        (const __attribute__((address_space(1))) void*)(pBbase + c * 64 + l * 2),
        (__attribute__((address_space(3))) void*)(&pBl[d][0]),
        4, 0, 0);
  };

  stage(0, 0);
  __syncthreads();

  float a0 = 0.f, a1 = 0.f, a2 = 0.f, a3 = 0.f, a4 = 0.f;
  if (l == 0) {
    a0 = __int_as_float(((unsigned)pBl[0][0]) << 16);  // t=0, s=0 (blank)
    a1 = __int_as_float(((unsigned)pO[0][0]) << 16);   // t=0, s=1 (y1)
  }
  int E = 0;

  const int nChunks = (len + 63) >> 6;
  for (int c = 0; c < nChunks; ++c) {
    const int d = c & 1;
    if ((c + 1) * 64 < len) stage(c + 1, 1 - d);

    const int stA = (c == 0) ? 1 : 0;
    const int stB = min(64, len - c * 64);
    const int n = stB - stA;

    auto ldL = [&](int st) -> unsigned {
      return *(const unsigned*)(&pO[d][(st << 7) + 2 * l]);
    };
    auto ldB = [&](int st) -> unsigned { return (unsigned)pBl[d][st]; };

    unsigned qL[4], qB[4];
#pragma unroll
    for (int k = 0; k < 4; ++k) {
      int st = stA + k; if (st > stB - 1) st = stB - 1;
      qL[k] = ldL(st); qB[k] = ldB(st);
    }

    auto body = [&](int i, int k) {
      const float pOa = __int_as_float(qL[k] << 16);           // label j=2l   (s=4l+1)
      const float pObv = __int_as_float(qL[k] & 0xffff0000u);  // label j=2l+1 (s=4l+3)
      const float pB = __int_as_float(qB[k] << 16);            // blank
      const float h3 = dpp_wshr1(a3);                          // alpha[4l-1] from lane l-1
      const float n0 = (a0 + h3) * pB;
      const float n1 = fmaf(sk1, h3, a1 + a0) * pOa;
      const float n2 = (a2 + a1) * pB;
      const float n3 = fmaf(sk3, a1, a3 + a2) * pObv;
      const float n4 = (a4 + a3) * pB;                         // state 256 (real on lane 63)
      a0 = n0; a1 = n1; a2 = n2; a3 = n3; a4 = n4;
      const int t = (c << 6) + stA + i;
      if ((t & 7) == 0) {  // exact pow2 renorm (uniform branch)
        float m = fmaxf(fmaxf(fmaxf(a0, a1), fmaxf(a2, a3)), a4);
        const float gm = dpp_wave_max(m);
        const int e = (int)((__float_as_uint(gm) >> 23) & 255) - 127;
        int sh = 60 - e; if (sh > 120) sh = 120;
        const float scale = __uint_as_float((unsigned)(127 + sh) << 23);
        E -= sh;
        a0 *= scale; a1 *= scale; a2 *= scale; a3 *= scale; a4 *= scale;
      }
      int st = stA + i + 4; if (st > stB - 1) st = stB - 1;
      qL[k] = ldL(st); qB[k] = ldB(st);
    };

    int i = 0;
    for (; i + 4 <= n; i += 4) { body(i, 0); body(i + 1, 1); body(i + 2, 2); body(i + 3, 3); }
    const int rrem = n & 3;
    if (rrem > 0) body(i, 0);
    if (rrem > 1) body(i + 1, 1);
    if (rrem > 2) body(i + 2, 2);
    __syncthreads();
  }

  const int tl = __popcll(__ballot(tg[l] != 0)) + __popcll(__ballot(tg[64 + l] != 0));
  const int s1 = 2 * tl - 1, s2 = 2 * tl;
  float v = 0.f;
  const int sb = 4 * l;
  if (sb == s1 || sb == s2) v += a0;
  if (sb + 1 == s1 || sb + 1 == s2) v += a1;
  if (sb + 2 == s1 || sb + 2 == s2) v += a2;
  if (sb + 3 == s1 || sb + 3 == s2) v += a3;
  if (l == 63 && s2 == 256) v += a4;
#pragma unroll
  for (int off = 1; off < 64; off <<= 1) v += __shfl_xor(v, off);
  if (l == 0)
    out[b] = -((log2f(v) + (float)E) * 0.6931471805599453f) / (float)tl;
}

// --------------------------------- launcher ---------------------------------
extern "C" void kernel_launch(void* const* d_in, const int* in_sizes, int n_in,
                              void* d_out, int out_size, void* d_ws, size_t ws_size,
                              hipStream_t stream) {
  const int*   targets = (const int*)d_in[0];
  const float* X       = (const float*)d_in[1];
  const int*   lens    = (const int*)d_in[2];
  const float* W1      = (const float*)d_in[3];
  const float* b1      = (const float*)d_in[4];
  const float* W2      = (const float*)d_in[5];
  const float* b2      = (const float*)d_in[6];
  float* out = (float*)d_out;

  // workspace layout (Xc aliases logits: disjoint live ranges)
  float*  logits  = (float*)d_ws;                        // CH*Vv fp32   (33.55 MB)
  ushort* Xc      = (ushort*)d_ws;                       // CH*Hh bf16   (aliased)
  ushort* h       = (ushort*)(logits + (size_t)CH * Vv); // CH*Hh bf16   (8.39 MB)
  ushort* W1T     = h + (size_t)CH * Hh;                 // Hh*Hh bf16
  ushort* W2T     = W1T + (size_t)Hh * Hh;               // Vv*Hh bf16
  ushort* pOddG   = W2T + (size_t)Hh * Vv;               // B*T*S bf16   (8.39 MB)
  ushort* pBlankG = pOddG + (size_t)Bq * Tt * Ss;        // B*T bf16 + 128 pad

  transpose_cvt<<<dim3(Hh / 32, Hh / 32), dim3(32, 8), 0, stream>>>(W1, W1T, Hh, Hh);
  transpose_cvt<<<dim3(Vv / 32, Hh / 32), dim3(32, 8), 0, stream>>>(W2, W2T, Hh, Vv);

  for (int c = 0; c < (Bq * Tt) / CH; ++c) {
    cvt_bf16<<<dim3((CH * Hh / 4) / 256), dim3(256), 0, stream>>>(
        X + (size_t)c * CH * Hh, Xc, CH * Hh / 4);
    gemm_mfma<true, true><<<dim3(Hh / 128, CH / 128), dim3(256), 0, stream>>>(
        Xc, W1T, b1, h, CH, Hh, Hh);
    gemm_mfma<false, false><<<dim3(Vv / 128, CH / 128), dim3(256), 0, stream>>>(
        h, W2T, b2, logits, CH, Vv, Hh);
    row_lse_gather<<<dim3(CH), dim3(256), 0, stream>>>(logits, targets, pBlankG, pOddG, c * CH);
  }
  ctc_dp<<<dim3(Bq), dim3(64), 0, stream>>>(pOddG, pBlankG, targets, lens, out);
}

// Round 5
// 313.814 us; speedup vs baseline: 4.1843x; 1.2671x over previous
//
#include <hip/hip_runtime.h>
#include <hip/hip_bf16.h>
#include <math.h>

#define Bq 32
#define Tt 1024
#define Hh 512
#define Vv 1024
#define Ss 128

typedef short bf16x8 __attribute__((ext_vector_type(8)));
typedef float f32x4 __attribute__((ext_vector_type(4)));

#define GLDS(srcp, dstp, sz) \
  __builtin_amdgcn_global_load_lds( \
      (const __attribute__((address_space(1))) void*)(srcp), \
      (__attribute__((address_space(3))) void*)(dstp), sz, 0, 0)

__device__ __forceinline__ ushort f2bf(float v) {
  __hip_bfloat16 hv = __float2bfloat16(v);
  return *(ushort*)&hv;
}

// butterfly reduce over 16-lane groups (r16) via ds_swizzle xor 1,2,4,8
#define BFLY_MAX(v) { \
  v = fmaxf(v, __int_as_float(__builtin_amdgcn_ds_swizzle(__float_as_int(v), 0x041F))); \
  v = fmaxf(v, __int_as_float(__builtin_amdgcn_ds_swizzle(__float_as_int(v), 0x081F))); \
  v = fmaxf(v, __int_as_float(__builtin_amdgcn_ds_swizzle(__float_as_int(v), 0x101F))); \
  v = fmaxf(v, __int_as_float(__builtin_amdgcn_ds_swizzle(__float_as_int(v), 0x201F))); }
#define BFLY_ADD(v) { \
  v += __int_as_float(__builtin_amdgcn_ds_swizzle(__float_as_int(v), 0x041F)); \
  v += __int_as_float(__builtin_amdgcn_ds_swizzle(__float_as_int(v), 0x081F)); \
  v += __int_as_float(__builtin_amdgcn_ds_swizzle(__float_as_int(v), 0x101F)); \
  v += __int_as_float(__builtin_amdgcn_ds_swizzle(__float_as_int(v), 0x201F)); }

// ---- transpose + fp32->bf16 : out[n][k] = in[k][n], in is [K][N] ----
__global__ void transpose_cvt(const float* __restrict__ in, ushort* __restrict__ out,
                              int K, int N) {
  __shared__ float tile[32][33];
  const int k0 = blockIdx.y * 32, n0 = blockIdx.x * 32;
  const int tx = threadIdx.x, ty = threadIdx.y;
  for (int i = ty; i < 32; i += 8)
    tile[i][tx] = in[(size_t)(k0 + i) * N + n0 + tx];
  __syncthreads();
  for (int i = ty; i < 32; i += 8)
    out[(size_t)(n0 + i) * K + k0 + tx] = f2bf(tile[tx][i]);
}

// ---- GEMM1: h = tanh(X @ W1T^T + b1), X fp32 (cvt in staging), out bf16 ----
__global__ __launch_bounds__(256)
void gemm1_fused(const float* __restrict__ A, const ushort* __restrict__ Bt,
                 const float* __restrict__ bias, ushort* __restrict__ H) {
  __shared__ ushort As[128 * 64];
  __shared__ ushort Bs[128 * 64];
  const int tid = threadIdx.x;
  const int lane = tid & 63, wave = tid >> 6;
  const int wm = wave >> 1, wn = wave & 1;
  const int q = lane >> 4, r16 = lane & 15;
  const int row0 = blockIdx.y * 128, col0 = blockIdx.x * 128;
  const int lrow = lane >> 3, lcol = (lane & 7) * 8;
  const int arow = tid >> 4;          // 0..15 (row within a 16-row pass)
  const int acol = (tid & 15) * 4;    // float col within 64

  f32x4 acc[4][4];
#pragma unroll
  for (int i = 0; i < 4; ++i)
#pragma unroll
    for (int j = 0; j < 4; ++j) acc[i][j] = (f32x4){0.f, 0.f, 0.f, 0.f};

  for (int kk = 0; kk < Hh; kk += 64) {
    __syncthreads();
    // A: fp32 -> bf16 staging via VGPR
#pragma unroll
    for (int p = 0; p < 8; ++p) {
      const int r = p * 16 + arow;
      const float4 f = *(const float4*)(A + (size_t)(row0 + r) * Hh + kk + acol);
      ushort4 u;
      u.x = f2bf(f.x); u.y = f2bf(f.y); u.z = f2bf(f.z); u.w = f2bf(f.w);
      *(ushort4*)&As[r * 64 + acol] = u;
    }
    // B: async global->LDS
#pragma unroll
    for (int i = 0; i < 4; ++i) {
      const int seg = wave * 4 + i;
      const int rr = seg * 8 + lrow;
      GLDS(Bt + (size_t)(col0 + rr) * Hh + kk + lcol, Bs + seg * 512, 16);
    }
    __syncthreads();
#pragma unroll
    for (int ks = 0; ks < 64; ks += 32) {
      bf16x8 af[4], bfr[4];
#pragma unroll
      for (int mi = 0; mi < 4; ++mi)
        af[mi] = *(const bf16x8*)(As + ((wm * 64 + mi * 16 + r16) << 6) + ks + q * 8);
#pragma unroll
      for (int ni = 0; ni < 4; ++ni)
        bfr[ni] = *(const bf16x8*)(Bs + ((wn * 64 + ni * 16 + r16) << 6) + ks + q * 8);
#pragma unroll
      for (int mi = 0; mi < 4; ++mi)
#pragma unroll
        for (int ni = 0; ni < 4; ++ni)
          acc[mi][ni] = __builtin_amdgcn_mfma_f32_16x16x32_bf16(af[mi], bfr[ni], acc[mi][ni], 0, 0, 0);
    }
  }
#pragma unroll
  for (int ni = 0; ni < 4; ++ni) {
    const int col = col0 + wn * 64 + ni * 16 + r16;
    const float bc = bias[col];
#pragma unroll
    for (int mi = 0; mi < 4; ++mi) {
#pragma unroll
      for (int r = 0; r < 4; ++r) {
        const int row = row0 + wm * 64 + mi * 16 + q * 4 + r;
        const float v = acc[mi][ni][r] + bc;
        // fast tanh: (e^2x - 1)/(e^2x + 1)
        const float ex = __expf(2.0f * v);
#if __has_builtin(__builtin_amdgcn_rcpf)
        const float rc = __builtin_amdgcn_rcpf(ex + 1.0f);
#else
        const float rc = 1.0f / (ex + 1.0f);
#endif
        H[(size_t)row * Hh + col] = f2bf((ex - 1.0f) * rc);
      }
    }
  }
}

// ---- GEMM2 + bias + online softmax + label gather, all fused ----
// One block per 128 rows (all rows belong to one example). A-frags in regs
// (full K=512), B double-buffered with cross-tile prefetch. 8 col-tiles for
// max/sum, then a 9th "label tile" (B-rows gathered via targets) directly
// produces pOdd/pBlank probabilities (prescaled by 2^6 for the CTC DP).
__global__ __launch_bounds__(256, 1)
void gemm2sm(const ushort* __restrict__ Aq, const ushort* __restrict__ Bt,
             const float* __restrict__ bias, const int* __restrict__ tgt,
             ushort* __restrict__ pOdd, ushort* __restrict__ pBlank) {
  __shared__ ushort Bs[2][128 * 64];          // 32 KB
  __shared__ float biasLds[Vv];               // 4 KB
  __shared__ int tgLds[128];
  __shared__ float rowM[128], rowS[128], sfArr[128], blankL[128];
  __shared__ float tmpM[2][128], tmpS[2][128];

  const int tid = threadIdx.x;
  const int lane = tid & 63, wave = tid >> 6;
  const int wm = wave >> 1, wn = wave & 1;
  const int q = lane >> 4, r16 = lane & 15;
  const int row0 = blockIdx.x * 128;
  const int bEx = blockIdx.x >> 3;
  const int lrow = lane >> 3, lcol = (lane & 7) * 8;

  // init staging
  GLDS(bias + tid * 4, (char*)biasLds + wave * 1024, 16);
  if (tid < 128) {
    tgLds[tid] = tgt[bEx * Ss + tid];
    rowM[tid] = -1e30f;
    rowS[tid] = 0.f;
  }

  // A fragments for whole K in registers: af[ks32][mi], 256 VGPRs
  bf16x8 af[16][4];
#pragma unroll
  for (int ks = 0; ks < 16; ++ks)
#pragma unroll
    for (int mi = 0; mi < 4; ++mi)
      af[ks][mi] = *(const bf16x8*)(Aq + (size_t)(row0 + wm * 64 + mi * 16 + r16) * Hh + ks * 32 + q * 8);

  auto stageB = [&](int nt, int kk, int d) {
#pragma unroll
    for (int i = 0; i < 4; ++i) {
      const int seg = wave * 4 + i;
      const int rr = seg * 8 + lrow;
      const ushort* src;
      if (nt < 8) src = Bt + (size_t)(nt * 128 + rr) * Hh + kk * 64 + lcol;
      else        src = Bt + (size_t)tgLds[rr] * Hh + kk * 64 + lcol;
      GLDS(src, &Bs[d][seg * 512], 16);
    }
  };

  stageB(0, 0, 0);

  f32x4 acc[4][4];
#pragma unroll
  for (int i = 0; i < 4; ++i)
#pragma unroll
    for (int j = 0; j < 4; ++j) acc[i][j] = (f32x4){0.f, 0.f, 0.f, 0.f};

  for (int nt = 0; nt < 9; ++nt) {
#pragma unroll
    for (int kk = 0; kk < 8; ++kk) {
      const int d = kk & 1;
      __syncthreads();   // prev buffer reads done; drains in-flight prefetch
      if (!(nt == 8 && kk == 7)) {
        const int ntn = (kk < 7) ? nt : nt + 1;
        const int kkn = (kk < 7) ? kk + 1 : 0;
        stageB(ntn, kkn, d ^ 1);
      }
#pragma unroll
      for (int ksl = 0; ksl < 2; ++ksl) {
        bf16x8 bfr[4];
#pragma unroll
        for (int ni = 0; ni < 4; ++ni)
          bfr[ni] = *(const bf16x8*)(&Bs[d][((wn * 64 + ni * 16 + r16) << 6) + ksl * 32 + q * 8]);
#pragma unroll
        for (int mi = 0; mi < 4; ++mi)
#pragma unroll
          for (int ni = 0; ni < 4; ++ni)
            acc[mi][ni] = __builtin_amdgcn_mfma_f32_16x16x32_bf16(af[kk * 2 + ksl][mi], bfr[ni], acc[mi][ni], 0, 0, 0);
      }
    }

    if (nt < 8) {
      // ---- online softmax epilogue for this tile ----
      float bcol[4];
#pragma unroll
      for (int ni = 0; ni < 4; ++ni) bcol[ni] = biasLds[nt * 128 + wn * 64 + ni * 16 + r16];

      float tm[4][4];
#pragma unroll
      for (int mi = 0; mi < 4; ++mi)
#pragma unroll
        for (int r = 0; r < 4; ++r) {
          float m = acc[mi][0][r] + bcol[0];
          m = fmaxf(m, acc[mi][1][r] + bcol[1]);
          m = fmaxf(m, acc[mi][2][r] + bcol[2]);
          m = fmaxf(m, acc[mi][3][r] + bcol[3]);
          BFLY_MAX(m);
          tm[mi][r] = m;
        }
      if (r16 == 0) {
#pragma unroll
        for (int mi = 0; mi < 4; ++mi) {
          float4 w = {tm[mi][0], tm[mi][1], tm[mi][2], tm[mi][3]};
          *(float4*)&tmpM[wn][wm * 64 + mi * 16 + q * 4] = w;
        }
        if (nt == 0 && wn == 0) {   // save blank-column logits (col 0)
#pragma unroll
          for (int mi = 0; mi < 4; ++mi) {
            float4 w = {acc[mi][0][0] + bcol[0], acc[mi][0][1] + bcol[0],
                        acc[mi][0][2] + bcol[0], acc[mi][0][3] + bcol[0]};
            *(float4*)&blankL[wm * 64 + mi * 16 + q * 4] = w;
          }
        }
      }
      __syncthreads();
      if (tid < 128) {
        const float old = rowM[tid];
        const float nm = fmaxf(old, fmaxf(tmpM[0][tid], tmpM[1][tid]));
        rowM[tid] = nm;
        sfArr[tid] = __expf(old - nm);
      }
      __syncthreads();
#pragma unroll
      for (int mi = 0; mi < 4; ++mi) {
        const float4 nm4 = *(const float4*)&rowM[wm * 64 + mi * 16 + q * 4];
#pragma unroll
        for (int r = 0; r < 4; ++r) {
          const float nm = ((const float*)&nm4)[r];
          float s = __expf(acc[mi][0][r] + bcol[0] - nm);
          s += __expf(acc[mi][1][r] + bcol[1] - nm);
          s += __expf(acc[mi][2][r] + bcol[2] - nm);
          s += __expf(acc[mi][3][r] + bcol[3] - nm);
          BFLY_ADD(s);
          tm[mi][r] = s;
        }
      }
      if (r16 == 0) {
#pragma unroll
        for (int mi = 0; mi < 4; ++mi) {
          float4 w = {tm[mi][0], tm[mi][1], tm[mi][2], tm[mi][3]};
          *(float4*)&tmpS[wn][wm * 64 + mi * 16 + q * 4] = w;
        }
      }
      __syncthreads();
      if (tid < 128)
        rowS[tid] = rowS[tid] * sfArr[tid] + tmpS[0][tid] + tmpS[1][tid];
      // zero acc for next tile
#pragma unroll
      for (int i = 0; i < 4; ++i)
#pragma unroll
        for (int j = 0; j < 4; ++j) acc[i][j] = (f32x4){0.f, 0.f, 0.f, 0.f};
    } else {
      // ---- label tile: emit probabilities (prescaled by 2^6) ----
      __syncthreads();
      if (tid < 128) {
        const float rc = rowM[tid] + __logf(rowS[tid]);
        sfArr[tid] = rc;
        pBlank[row0 + tid] = f2bf(__expf(blankL[tid] - rc) * 64.0f);
      }
      __syncthreads();
      float bcl[4];
#pragma unroll
      for (int ni = 0; ni < 4; ++ni) bcl[ni] = biasLds[tgLds[wn * 64 + ni * 16 + r16]];
#pragma unroll
      for (int mi = 0; mi < 4; ++mi) {
        const float4 rc4 = *(const float4*)&sfArr[wm * 64 + mi * 16 + q * 4];
#pragma unroll
        for (int r = 0; r < 4; ++r) {
          const float rc = ((const float*)&rc4)[r];
          const int row = row0 + wm * 64 + mi * 16 + q * 4 + r;
#pragma unroll
          for (int ni = 0; ni < 4; ++ni) {
            const float p = __expf(acc[mi][ni][r] + bcl[ni] - rc) * 64.0f;
            pOdd[(size_t)row * Ss + wn * 64 + ni * 16 + r16] = f2bf(p);
          }
        }
      }
    }
  }
}

// ---- DPP helpers ----
__device__ __forceinline__ float dpp_wshr1(float x) {
  return __int_as_float(__builtin_amdgcn_update_dpp(
      0, __float_as_int(x), 0x138, 0xf, 0xf, true));
}
__device__ __forceinline__ float dpp_wave_max(float m) {
  m = fmaxf(m, __int_as_float(__builtin_amdgcn_update_dpp(0, __float_as_int(m), 0x111, 0xf, 0xf, true)));
  m = fmaxf(m, __int_as_float(__builtin_amdgcn_update_dpp(0, __float_as_int(m), 0x112, 0xf, 0xf, true)));
  m = fmaxf(m, __int_as_float(__builtin_amdgcn_update_dpp(0, __float_as_int(m), 0x114, 0xf, 0xf, true)));
  m = fmaxf(m, __int_as_float(__builtin_amdgcn_update_dpp(0, __float_as_int(m), 0x118, 0xf, 0xf, true)));
  m = fmaxf(m, __int_as_float(__builtin_amdgcn_update_dpp(__float_as_int(m), __float_as_int(m), 0x142, 0xf, 0xf, false)));
  m = fmaxf(m, __int_as_float(__builtin_amdgcn_update_dpp(__float_as_int(m), __float_as_int(m), 0x143, 0xf, 0xf, false)));
  return __int_as_float(__builtin_amdgcn_readlane(__float_as_int(m), 63));
}

// ---- CTC forward DP (probs prescaled by 2^6; renorm every 16 steps) ----
__global__ __launch_bounds__(64)
void ctc_dp(const ushort* __restrict__ pOddG, const ushort* __restrict__ pBlankG,
            const int* __restrict__ tgt, const int* __restrict__ lens,
            float* __restrict__ out) {
  __shared__ ushort pO[2][64 * 128];
  __shared__ ushort pBl[2][128];
  const int b = blockIdx.x, l = threadIdx.x;
  const ushort* pObase = pOddG + (size_t)b * Tt * Ss;
  const ushort* pBbase = pBlankG + (size_t)b * Tt;
  const int* tg = tgt + b * Ss;
  const int len = lens[b];

  float sk1 = 0.f, sk3 = 0.f;
  if (l >= 1) sk1 = (tg[2 * l] != tg[2 * l - 1]) ? 1.f : 0.f;
  sk3 = (tg[2 * l + 1] != tg[2 * l]) ? 1.f : 0.f;

  auto stage = [&](int c, int d) {
    const ushort* src = pObase + (size_t)c * 64 * 128;
#pragma unroll
    for (int i = 0; i < 16; ++i)
      GLDS(src + (i * 64 + l) * 8, &pO[d][i * 512], 16);
    GLDS(pBbase + c * 64 + l * 2, &pBl[d][0], 4);
  };

  stage(0, 0);
  __syncthreads();

  float a0 = 0.f, a1 = 0.f, a2 = 0.f, a3 = 0.f, a4 = 0.f;
  if (l == 0) {
    a0 = __int_as_float(((unsigned)pBl[0][0]) << 16);
    a1 = __int_as_float(((unsigned)pO[0][0]) << 16);
  }
  int E = 0;

  const int nChunks = (len + 63) >> 6;
  for (int c = 0; c < nChunks; ++c) {
    const int d = c & 1;
    if ((c + 1) * 64 < len) stage(c + 1, 1 - d);

    const int stA = (c == 0) ? 1 : 0;
    const int stB = min(64, len - c * 64);
    const int n = stB - stA;

    auto ldL = [&](int st) -> unsigned {
      return *(const unsigned*)(&pO[d][(st << 7) + 2 * l]);
    };
    auto ldB = [&](int st) -> unsigned { return (unsigned)pBl[d][st]; };

    unsigned qL[4], qB[4];
#pragma unroll
    for (int k = 0; k < 4; ++k) {
      int st = stA + k; if (st > stB - 1) st = stB - 1;
      qL[k] = ldL(st); qB[k] = ldB(st);
    }

    auto body = [&](int i, int k) {
      const float pOa = __int_as_float(qL[k] << 16);
      const float pObv = __int_as_float(qL[k] & 0xffff0000u);
      const float pB = __int_as_float(qB[k] << 16);
      const float h3 = dpp_wshr1(a3);
      const float n0 = (a0 + h3) * pB;
      const float n1 = fmaf(sk1, h3, a1 + a0) * pOa;
      const float n2 = (a2 + a1) * pB;
      const float n3 = fmaf(sk3, a1, a3 + a2) * pObv;
      const float n4 = (a4 + a3) * pB;
      a0 = n0; a1 = n1; a2 = n2; a3 = n3; a4 = n4;
      const int t = (c << 6) + stA + i;
      if ((t & 15) == 0) {  // exact pow2 renorm, target 2^40
        float m = fmaxf(fmaxf(fmaxf(a0, a1), fmaxf(a2, a3)), a4);
        const float gm = dpp_wave_max(m);
        const int e = (int)((__float_as_uint(gm) >> 23) & 255) - 127;
        int sh = 40 - e; if (sh > 120) sh = 120;
        const float scale = __uint_as_float((unsigned)(127 + sh) << 23);
        E -= sh;
        a0 *= scale; a1 *= scale; a2 *= scale; a3 *= scale; a4 *= scale;
      }
      int st = stA + i + 4; if (st > stB - 1) st = stB - 1;
      qL[k] = ldL(st); qB[k] = ldB(st);
    };

    int i = 0;
    for (; i + 4 <= n; i += 4) { body(i, 0); body(i + 1, 1); body(i + 2, 2); body(i + 3, 3); }
    const int rrem = n & 3;
    if (rrem > 0) body(i, 0);
    if (rrem > 1) body(i + 1, 1);
    if (rrem > 2) body(i + 2, 2);
    __syncthreads();
  }

  const int tl = __popcll(__ballot(tg[l] != 0)) + __popcll(__ballot(tg[64 + l] != 0));
  const int s1 = 2 * tl - 1, s2 = 2 * tl;
  float v = 0.f;
  const int sb = 4 * l;
  if (sb == s1 || sb == s2) v += a0;
  if (sb + 1 == s1 || sb + 1 == s2) v += a1;
  if (sb + 2 == s1 || sb + 2 == s2) v += a2;
  if (sb + 3 == s1 || sb + 3 == s2) v += a3;
  if (l == 63 && s2 == 256) v += a4;
#pragma unroll
  for (int off = 1; off < 64; off <<= 1) v += __shfl_xor(v, off);
  if (l == 0)
    out[b] = -((log2f(v) + (float)E - 6.0f * (float)len) * 0.6931471805599453f) / (float)tl;
}

// --------------------------------- launcher ---------------------------------
extern "C" void kernel_launch(void* const* d_in, const int* in_sizes, int n_in,
                              void* d_out, int out_size, void* d_ws, size_t ws_size,
                              hipStream_t stream) {
  const int*   targets = (const int*)d_in[0];
  const float* X       = (const float*)d_in[1];
  const int*   lens    = (const int*)d_in[2];
  const float* W1      = (const float*)d_in[3];
  const float* b1      = (const float*)d_in[4];
  const float* W2      = (const float*)d_in[5];
  const float* b2      = (const float*)d_in[6];
  float* out = (float*)d_out;

  ushort* h       = (ushort*)d_ws;                       // 32768*512 bf16 (33.55 MB)
  ushort* W1T     = h + (size_t)Bq * Tt * Hh;            // 512*512 bf16
  ushort* W2T     = W1T + (size_t)Hh * Hh;               // 1024*512 bf16
  ushort* pOddG   = W2T + (size_t)Vv * Hh;               // 32768*128 bf16 (8.39 MB)
  ushort* pBlankG = pOddG + (size_t)Bq * Tt * Ss;        // 32768 bf16 (+pad tail)

  transpose_cvt<<<dim3(Hh / 32, Hh / 32), dim3(32, 8), 0, stream>>>(W1, W1T, Hh, Hh);
  transpose_cvt<<<dim3(Vv / 32, Hh / 32), dim3(32, 8), 0, stream>>>(W2, W2T, Hh, Vv);
  gemm1_fused<<<dim3(Hh / 128, (Bq * Tt) / 128), dim3(256), 0, stream>>>(X, W1T, b1, h);
  gemm2sm<<<dim3((Bq * Tt) / 128), dim3(256), 0, stream>>>(h, W2T, b2, targets, pOddG, pBlankG);
  ctc_dp<<<dim3(Bq), dim3(64), 0, stream>>>(pOddG, pBlankG, targets, lens, out);
}

// Round 6
// 271.644 us; speedup vs baseline: 4.8339x; 1.1552x over previous
//
#include <hip/hip_runtime.h>
#include <hip/hip_bf16.h>
#include <math.h>

#define Bq 32
#define Tt 1024
#define Hh 512
#define Vv 1024
#define Ss 128

typedef short bf16x8 __attribute__((ext_vector_type(8)));
typedef float f32x4 __attribute__((ext_vector_type(4)));

#define GLDS(srcp, dstp, sz) \
  __builtin_amdgcn_global_load_lds( \
      (const __attribute__((address_space(1))) void*)(srcp), \
      (__attribute__((address_space(3))) void*)(dstp), sz, 0, 0)

__device__ __forceinline__ ushort f2bf(float v) {
  __hip_bfloat16 hv = __float2bfloat16(v);
  return *(ushort*)&hv;
}

// butterfly reduce over 16-lane groups via ds_swizzle xor 1,2,4,8
#define BFLY_MAX(v) { \
  v = fmaxf(v, __int_as_float(__builtin_amdgcn_ds_swizzle(__float_as_int(v), 0x041F))); \
  v = fmaxf(v, __int_as_float(__builtin_amdgcn_ds_swizzle(__float_as_int(v), 0x081F))); \
  v = fmaxf(v, __int_as_float(__builtin_amdgcn_ds_swizzle(__float_as_int(v), 0x101F))); \
  v = fmaxf(v, __int_as_float(__builtin_amdgcn_ds_swizzle(__float_as_int(v), 0x201F))); }
#define BFLY_ADD(v) { \
  v += __int_as_float(__builtin_amdgcn_ds_swizzle(__float_as_int(v), 0x041F)); \
  v += __int_as_float(__builtin_amdgcn_ds_swizzle(__float_as_int(v), 0x081F)); \
  v += __int_as_float(__builtin_amdgcn_ds_swizzle(__float_as_int(v), 0x101F)); \
  v += __int_as_float(__builtin_amdgcn_ds_swizzle(__float_as_int(v), 0x201F)); }

// ---- transpose + fp32->bf16 : out[n][k] = in[k][n], in is [K][N] ----
__global__ void transpose_cvt(const float* __restrict__ in, ushort* __restrict__ out,
                              int K, int N) {
  __shared__ float tile[32][33];
  const int k0 = blockIdx.y * 32, n0 = blockIdx.x * 32;
  const int tx = threadIdx.x, ty = threadIdx.y;
  for (int i = ty; i < 32; i += 8)
    tile[i][tx] = in[(size_t)(k0 + i) * N + n0 + tx];
  __syncthreads();
  for (int i = ty; i < 32; i += 8)
    out[(size_t)(n0 + i) * K + k0 + tx] = f2bf(tile[tx][i]);
}

// ---- GEMM1: h = tanh(X @ W1T^T + b1) ----
// 128x128 tile, fully double-buffered (A via regs->LDS, B via GLDS), 1 barrier/kk,
// XOR-swizzled LDS k-chunks (slot c of row r holds global chunk c^(r&7)).
__global__ __launch_bounds__(256, 2)
void gemm1_fused(const float* __restrict__ A, const ushort* __restrict__ Bt,
                 const float* __restrict__ bias, ushort* __restrict__ H) {
  __shared__ ushort As[2][128 * 64];
  __shared__ ushort Bs[2][128 * 64];
  const int tid = threadIdx.x;
  const int lane = tid & 63, wave = tid >> 6;
  const int wm = wave >> 1, wn = wave & 1;
  const int q = lane >> 4, r16 = lane & 15;
  const int row0 = blockIdx.y * 128, col0 = blockIdx.x * 128;
  const int lrow = lane >> 3;
  const int swz = (lane & 7) ^ lrow;       // global chunk for B staging slot
  const int ra_ = tid >> 3;                // 0..31  A-staging row (per 32-row pass)
  const int ca_ = tid & 7;                 // A-staging chunk slot
  const int ga_ = ca_ ^ (ra_ & 7);         // global chunk held by that slot
  const int rx = r16 & 7;
  const int kx0 = (q ^ rx) * 8;            // swizzled frag offsets (ksl=0/1)
  const int kx1 = ((4 + q) ^ rx) * 8;

  float4 rA[4][2];
  auto loadA = [&](int kk) {
#pragma unroll
    for (int p = 0; p < 4; ++p) {
      const float* src = A + (size_t)(row0 + p * 32 + ra_) * Hh + kk * 64 + ga_ * 8;
      rA[p][0] = *(const float4*)(src);
      rA[p][1] = *(const float4*)(src + 4);
    }
  };
  auto storeA = [&](int d) {
#pragma unroll
    for (int p = 0; p < 4; ++p) {
      unsigned w0 = ((unsigned)f2bf(rA[p][0].y) << 16) | f2bf(rA[p][0].x);
      unsigned w1 = ((unsigned)f2bf(rA[p][0].w) << 16) | f2bf(rA[p][0].z);
      unsigned w2 = ((unsigned)f2bf(rA[p][1].y) << 16) | f2bf(rA[p][1].x);
      unsigned w3 = ((unsigned)f2bf(rA[p][1].w) << 16) | f2bf(rA[p][1].z);
      uint4 u = {w0, w1, w2, w3};
      *(uint4*)&As[d][(p * 32 + ra_) * 64 + ca_ * 8] = u;
    }
  };
  auto stageB = [&](int kk, int d) {
#pragma unroll
    for (int i = 0; i < 4; ++i) {
      const int seg = wave * 4 + i;
      const int rr = seg * 8 + lrow;
      GLDS(Bt + (size_t)(col0 + rr) * Hh + kk * 64 + swz * 8, &Bs[d][seg * 512], 16);
    }
  };

  f32x4 acc[4][4];
#pragma unroll
  for (int i = 0; i < 4; ++i)
#pragma unroll
    for (int j = 0; j < 4; ++j) acc[i][j] = (f32x4){0.f, 0.f, 0.f, 0.f};

  loadA(0);
  stageB(0, 0);
  storeA(0);
  loadA(1);
  __syncthreads();

  for (int kk = 0; kk < 8; ++kk) {
    const int d = kk & 1;
    if (kk < 7) { stageB(kk + 1, d ^ 1); storeA(d ^ 1); }
    if (kk < 6) loadA(kk + 2);
#pragma unroll
    for (int ksl = 0; ksl < 2; ++ksl) {
      const int kxo = ksl ? kx1 : kx0;
      bf16x8 af[4], bfr[4];
#pragma unroll
      for (int mi = 0; mi < 4; ++mi)
        af[mi] = *(const bf16x8*)(&As[d][((wm * 64 + mi * 16 + r16) << 6) + kxo]);
#pragma unroll
      for (int ni = 0; ni < 4; ++ni)
        bfr[ni] = *(const bf16x8*)(&Bs[d][((wn * 64 + ni * 16 + r16) << 6) + kxo]);
#pragma unroll
      for (int mi = 0; mi < 4; ++mi)
#pragma unroll
        for (int ni = 0; ni < 4; ++ni)
          acc[mi][ni] = __builtin_amdgcn_mfma_f32_16x16x32_bf16(af[mi], bfr[ni], acc[mi][ni], 0, 0, 0);
    }
    __syncthreads();
  }

#pragma unroll
  for (int ni = 0; ni < 4; ++ni) {
    const int col = col0 + wn * 64 + ni * 16 + r16;
    const float bc = bias[col];
#pragma unroll
    for (int mi = 0; mi < 4; ++mi) {
#pragma unroll
      for (int r = 0; r < 4; ++r) {
        const int row = row0 + wm * 64 + mi * 16 + q * 4 + r;
        const float v = acc[mi][ni][r] + bc;
        const float ex = __expf(2.0f * v);     // tanh = (e^2x-1)/(e^2x+1)
        const float rc = 1.0f / (ex + 1.0f);
        H[(size_t)row * Hh + col] = f2bf((ex - 1.0f) * rc);
      }
    }
  }
}

// ---- GEMM2 + bias + online softmax + label gather, fused ----
// 64 rows/block (grid 512 -> 2 blocks/CU), A-frags in regs (full K),
// B double-buffered via GLDS with XOR swizzle; 8 col-passes + label pass.
__global__ __launch_bounds__(256, 2)
void gemm2sm(const ushort* __restrict__ Aq, const ushort* __restrict__ Bt,
             const float* __restrict__ bias, const int* __restrict__ tgt,
             ushort* __restrict__ pOdd, ushort* __restrict__ pBlank) {
  __shared__ ushort Bs[2][128 * 64];          // 32 KB
  __shared__ float biasLds[Vv];               // 4 KB
  __shared__ int tgLds[128];
  __shared__ float rowM[64], rowS[64], sfArr[64], blankL[64];
  __shared__ float tmpM[2][64], tmpS[2][64];

  const int tid = threadIdx.x;
  const int lane = tid & 63, wave = tid >> 6;
  const int wm = wave >> 1, wn = wave & 1;
  const int q = lane >> 4, r16 = lane & 15;
  const int row0 = blockIdx.x * 64;
  const int bEx = blockIdx.x >> 4;
  const int lrow = lane >> 3;
  const int swz = (lane & 7) ^ lrow;
  const int rx = r16 & 7;
  const int kx0 = (q ^ rx) * 8;
  const int kx1 = ((4 + q) ^ rx) * 8;

  GLDS(bias + tid * 4, (char*)biasLds + wave * 1024, 16);
  if (tid < 128) tgLds[tid] = tgt[bEx * Ss + tid];
  if (tid < 64) { rowM[tid] = -1e30f; rowS[tid] = 0.f; }

  // A fragments for the whole K: af[ks][mi] = rows row0+wm*32+mi*16+r16
  bf16x8 af[16][2];
#pragma unroll
  for (int ks = 0; ks < 16; ++ks)
#pragma unroll
    for (int mi = 0; mi < 2; ++mi)
      af[ks][mi] = *(const bf16x8*)(Aq + (size_t)(row0 + wm * 32 + mi * 16 + r16) * Hh + ks * 32 + q * 8);

  auto stageB = [&](int nt, int kk, int d) {
#pragma unroll
    for (int i = 0; i < 4; ++i) {
      const int seg = wave * 4 + i;
      const int rr = seg * 8 + lrow;
      const int kko = kk * 64 + swz * 8;
      const ushort* src;
      if (nt < 8) src = Bt + (size_t)(nt * 128 + rr) * Hh + kko;
      else        src = Bt + (size_t)tgLds[rr] * Hh + kko;
      GLDS(src, &Bs[d][seg * 512], 16);
    }
  };

  stageB(0, 0, 0);

  f32x4 acc[2][4];
#pragma unroll
  for (int i = 0; i < 2; ++i)
#pragma unroll
    for (int j = 0; j < 4; ++j) acc[i][j] = (f32x4){0.f, 0.f, 0.f, 0.f};

  for (int nt = 0; nt < 9; ++nt) {
#pragma unroll
    for (int kk = 0; kk < 8; ++kk) {
      const int d = kk & 1;
      __syncthreads();
      if (!(nt == 8 && kk == 7)) {
        const int ntn = (kk < 7) ? nt : nt + 1;
        const int kkn = (kk < 7) ? kk + 1 : 0;
        stageB(ntn, kkn, d ^ 1);
      }
#pragma unroll
      for (int ksl = 0; ksl < 2; ++ksl) {
        const int kxo = ksl ? kx1 : kx0;
        bf16x8 bfr[4];
#pragma unroll
        for (int ni = 0; ni < 4; ++ni)
          bfr[ni] = *(const bf16x8*)(&Bs[d][((wn * 64 + ni * 16 + r16) << 6) + kxo]);
#pragma unroll
        for (int mi = 0; mi < 2; ++mi)
#pragma unroll
          for (int ni = 0; ni < 4; ++ni)
            acc[mi][ni] = __builtin_amdgcn_mfma_f32_16x16x32_bf16(af[kk * 2 + ksl][mi], bfr[ni], acc[mi][ni], 0, 0, 0);
      }
    }

    if (nt < 8) {
      float bcol[4];
#pragma unroll
      for (int ni = 0; ni < 4; ++ni) bcol[ni] = biasLds[nt * 128 + wn * 64 + ni * 16 + r16];

      float tm[2][4];
#pragma unroll
      for (int mi = 0; mi < 2; ++mi)
#pragma unroll
        for (int r = 0; r < 4; ++r) {
          float m = acc[mi][0][r] + bcol[0];
          m = fmaxf(m, acc[mi][1][r] + bcol[1]);
          m = fmaxf(m, acc[mi][2][r] + bcol[2]);
          m = fmaxf(m, acc[mi][3][r] + bcol[3]);
          BFLY_MAX(m);
          tm[mi][r] = m;
        }
      if (r16 == 0) {
#pragma unroll
        for (int mi = 0; mi < 2; ++mi) {
          float4 w = {tm[mi][0], tm[mi][1], tm[mi][2], tm[mi][3]};
          *(float4*)&tmpM[wn][wm * 32 + mi * 16 + q * 4] = w;
        }
        if (nt == 0 && wn == 0) {
#pragma unroll
          for (int mi = 0; mi < 2; ++mi) {
            float4 w = {acc[mi][0][0] + bcol[0], acc[mi][0][1] + bcol[0],
                        acc[mi][0][2] + bcol[0], acc[mi][0][3] + bcol[0]};
            *(float4*)&blankL[wm * 32 + mi * 16 + q * 4] = w;
          }
        }
      }
      __syncthreads();
      if (tid < 64) {
        const float old = rowM[tid];
        const float nm = fmaxf(old, fmaxf(tmpM[0][tid], tmpM[1][tid]));
        rowM[tid] = nm;
        sfArr[tid] = __expf(old - nm);
      }
      __syncthreads();
#pragma unroll
      for (int mi = 0; mi < 2; ++mi) {
        const float4 nm4 = *(const float4*)&rowM[wm * 32 + mi * 16 + q * 4];
#pragma unroll
        for (int r = 0; r < 4; ++r) {
          const float nm = ((const float*)&nm4)[r];
          float s = __expf(acc[mi][0][r] + bcol[0] - nm);
          s += __expf(acc[mi][1][r] + bcol[1] - nm);
          s += __expf(acc[mi][2][r] + bcol[2] - nm);
          s += __expf(acc[mi][3][r] + bcol[3] - nm);
          BFLY_ADD(s);
          tm[mi][r] = s;
        }
      }
      if (r16 == 0) {
#pragma unroll
        for (int mi = 0; mi < 2; ++mi) {
          float4 w = {tm[mi][0], tm[mi][1], tm[mi][2], tm[mi][3]};
          *(float4*)&tmpS[wn][wm * 32 + mi * 16 + q * 4] = w;
        }
      }
      __syncthreads();
      if (tid < 64)
        rowS[tid] = rowS[tid] * sfArr[tid] + tmpS[0][tid] + tmpS[1][tid];
#pragma unroll
      for (int i = 0; i < 2; ++i)
#pragma unroll
        for (int j = 0; j < 4; ++j) acc[i][j] = (f32x4){0.f, 0.f, 0.f, 0.f};
    } else {
      __syncthreads();
      if (tid < 64) {
        const float rc = rowM[tid] + __logf(rowS[tid]);
        sfArr[tid] = rc;
        pBlank[row0 + tid] = f2bf(__expf(blankL[tid] - rc) * 64.0f);
      }
      __syncthreads();
      float bcl[4];
#pragma unroll
      for (int ni = 0; ni < 4; ++ni) bcl[ni] = biasLds[tgLds[wn * 64 + ni * 16 + r16]];
#pragma unroll
      for (int mi = 0; mi < 2; ++mi) {
        const float4 rc4 = *(const float4*)&sfArr[wm * 32 + mi * 16 + q * 4];
#pragma unroll
        for (int r = 0; r < 4; ++r) {
          const float rc = ((const float*)&rc4)[r];
          const int row = row0 + wm * 32 + mi * 16 + q * 4 + r;
#pragma unroll
          for (int ni = 0; ni < 4; ++ni) {
            const float p = __expf(acc[mi][ni][r] + bcl[ni] - rc) * 64.0f;
            pOdd[(size_t)row * Ss + wn * 64 + ni * 16 + r16] = f2bf(p);
          }
        }
      }
    }
  }
}

// ---- DPP helpers ----
__device__ __forceinline__ float dpp_wshr1(float x) {
  return __int_as_float(__builtin_amdgcn_update_dpp(
      0, __float_as_int(x), 0x138, 0xf, 0xf, true));
}
__device__ __forceinline__ float dpp_wave_max(float m) {
  m = fmaxf(m, __int_as_float(__builtin_amdgcn_update_dpp(0, __float_as_int(m), 0x111, 0xf, 0xf, true)));
  m = fmaxf(m, __int_as_float(__builtin_amdgcn_update_dpp(0, __float_as_int(m), 0x112, 0xf, 0xf, true)));
  m = fmaxf(m, __int_as_float(__builtin_amdgcn_update_dpp(0, __float_as_int(m), 0x114, 0xf, 0xf, true)));
  m = fmaxf(m, __int_as_float(__builtin_amdgcn_update_dpp(0, __float_as_int(m), 0x118, 0xf, 0xf, true)));
  m = fmaxf(m, __int_as_float(__builtin_amdgcn_update_dpp(__float_as_int(m), __float_as_int(m), 0x142, 0xf, 0xf, false)));
  m = fmaxf(m, __int_as_float(__builtin_amdgcn_update_dpp(__float_as_int(m), __float_as_int(m), 0x143, 0xf, 0xf, false)));
  return __int_as_float(__builtin_amdgcn_readlane(__float_as_int(m), 63));
}

// ---- CTC forward DP: 4 states/lane (+256 on lane63), DPP halo,
// padded double-buffered LDS staging, 8-deep pipeline, unrolled 64-step chunks.
__global__ __launch_bounds__(64)
void ctc_dp(const ushort* __restrict__ pOddG, const ushort* __restrict__ pBlankG,
            const int* __restrict__ tgt, const int* __restrict__ lens,
            float* __restrict__ out) {
  __shared__ ushort pO[2][72 * 128];   // 64 staged + 8 pad rows (prefetch overrun)
  __shared__ ushort pBl[2][128];
  const int b = blockIdx.x, l = threadIdx.x;
  const ushort* pObase = pOddG + (size_t)b * Tt * Ss;
  const ushort* pBbase = pBlankG + (size_t)b * Tt;
  const int* tg = tgt + b * Ss;
  const int len = lens[b];

  float sk1 = 0.f, sk3;
  if (l >= 1) sk1 = (tg[2 * l] != tg[2 * l - 1]) ? 1.f : 0.f;
  sk3 = (tg[2 * l + 1] != tg[2 * l]) ? 1.f : 0.f;

  auto stage = [&](int c, int d) {
    const ushort* src = pObase + (size_t)c * 64 * 128;
#pragma unroll
    for (int i = 0; i < 16; ++i)
      GLDS(src + (i * 64 + l) * 8, &pO[d][i * 512], 16);
    GLDS(pBbase + c * 64 + l * 2, &pBl[d][0], 4);
  };

  stage(0, 0);
  __syncthreads();

  float a0 = 0.f, a1 = 0.f, a2 = 0.f, a3 = 0.f, a4 = 0.f;
  if (l == 0) {
    a0 = __int_as_float(((unsigned)pBl[0][0]) << 16);
    a1 = __int_as_float(((unsigned)pO[0][0]) << 16);
  }
  int E = 0;

  auto renorm = [&]() {   // exact pow2 renorm, target 2^30, every 8 steps
    float m = fmaxf(fmaxf(fmaxf(a0, a1), fmaxf(a2, a3)), a4);
    const float gm = dpp_wave_max(m);
    const int e = (int)((__float_as_uint(gm) >> 23) & 255) - 127;
    int sh = 30 - e; if (sh > 120) sh = 120;
    const float scale = __uint_as_float((unsigned)(127 + sh) << 23);
    E -= sh;
    a0 *= scale; a1 *= scale; a2 *= scale; a3 *= scale; a4 *= scale;
  };

  auto run_dyn = [&](int d, int stA, int stB, int tbase) {
    const int n = stB - stA;
    if (n <= 0) return;
    unsigned qL[4], qB[4];
#pragma unroll
    for (int k = 0; k < 4; ++k) {
      const int st = stA + k;
      qL[k] = *(const unsigned*)&pO[d][(st << 7) + 2 * l];
      qB[k] = (unsigned)pBl[d][st];
    }
    auto body = [&](int i, int k) {
      const float pOa = __int_as_float(qL[k] << 16);
      const float pObv = __int_as_float(qL[k] & 0xffff0000u);
      const float pB = __int_as_float(qB[k] << 16);
      const float h3 = dpp_wshr1(a3);
      const float n0 = (a0 + h3) * pB;
      const float n1 = fmaf(sk1, h3, a1 + a0) * pOa;
      const float n2 = (a2 + a1) * pB;
      const float n3 = fmaf(sk3, a1, a3 + a2) * pObv;
      const float n4 = (a4 + a3) * pB;
      a0 = n0; a1 = n1; a2 = n2; a3 = n3; a4 = n4;
      const int st2 = stA + i + 4;
      qL[k] = *(const unsigned*)&pO[d][(st2 << 7) + 2 * l];
      qB[k] = (unsigned)pBl[d][st2];
      if (((tbase + i) & 7) == 0) renorm();
    };
    int i = 0;
    for (; i + 4 <= n; i += 4) { body(i, 0); body(i + 1, 1); body(i + 2, 2); body(i + 3, 3); }
    if ((n & 3) > 0) body(i, 0);
    if ((n & 3) > 1) body(i + 1, 1);
    if ((n & 3) > 2) body(i + 2, 2);
  };

  auto run_full = [&](int d) {   // exactly 64 steps, stA=0
    unsigned qL[8], qB[4];
#pragma unroll
    for (int k = 0; k < 8; ++k)
      qL[k] = *(const unsigned*)&pO[d][(k << 7) + 2 * l];
#pragma unroll
    for (int j = 0; j < 4; ++j)
      qB[j] = *(const unsigned*)&pBl[d][2 * j];
    for (int i = 0; i < 64; i += 8) {
#pragma unroll
      for (int k = 0; k < 8; ++k) {
        const float pOa = __int_as_float(qL[k] << 16);
        const float pObv = __int_as_float(qL[k] & 0xffff0000u);
        const unsigned bb = qB[k >> 1];
        const float pB = __int_as_float((k & 1) ? (bb & 0xffff0000u) : (bb << 16));
        const float h3 = dpp_wshr1(a3);
        const float n0 = (a0 + h3) * pB;
        const float n1 = fmaf(sk1, h3, a1 + a0) * pOa;
        const float n2 = (a2 + a1) * pB;
        const float n3 = fmaf(sk3, a1, a3 + a2) * pObv;
        const float n4 = (a4 + a3) * pB;
        a0 = n0; a1 = n1; a2 = n2; a3 = n3; a4 = n4;
        qL[k] = *(const unsigned*)&pO[d][((i + k + 8) << 7) + 2 * l];
        if (k & 1) qB[k >> 1] = *(const unsigned*)&pBl[d][i + k + 7];
        if (k == 0) renorm();
      }
    }
  };

  // chunk 0 (steps 1..min(64,len)-1)
  if (64 < len) stage(1, 1);
  run_dyn(0, 1, (64 < len) ? 64 : len, 1);
  __syncthreads();
  const int Cfull = len >> 6;
  for (int c = 1; c < Cfull; ++c) {
    const int d = c & 1;
    if ((c + 1) * 64 < len) stage(c + 1, d ^ 1);
    run_full(d);
    __syncthreads();
  }
  if (len & 63) run_dyn(Cfull & 1, 0, len & 63, Cfull * 64);

  const int tl = __popcll(__ballot(tg[l] != 0)) + __popcll(__ballot(tg[64 + l] != 0));
  const int s1 = 2 * tl - 1, s2 = 2 * tl;
  float v = 0.f;
  const int sb = 4 * l;
  if (sb == s1 || sb == s2) v += a0;
  if (sb + 1 == s1 || sb + 1 == s2) v += a1;
  if (sb + 2 == s1 || sb + 2 == s2) v += a2;
  if (sb + 3 == s1 || sb + 3 == s2) v += a3;
  if (l == 63 && s2 == 256) v += a4;
#pragma unroll
  for (int off = 1; off < 64; off <<= 1) v += __shfl_xor(v, off);
  if (l == 0)
    out[b] = -((log2f(v) + (float)E - 6.0f * (float)len) * 0.6931471805599453f) / (float)tl;
}

// --------------------------------- launcher ---------------------------------
extern "C" void kernel_launch(void* const* d_in, const int* in_sizes, int n_in,
                              void* d_out, int out_size, void* d_ws, size_t ws_size,
                              hipStream_t stream) {
  const int*   targets = (const int*)d_in[0];
  const float* X       = (const float*)d_in[1];
  const int*   lens    = (const int*)d_in[2];
  const float* W1      = (const float*)d_in[3];
  const float* b1      = (const float*)d_in[4];
  const float* W2      = (const float*)d_in[5];
  const float* b2      = (const float*)d_in[6];
  float* out = (float*)d_out;

  ushort* h       = (ushort*)d_ws;                       // 32768*512 bf16 (33.55 MB)
  ushort* W1T     = h + (size_t)Bq * Tt * Hh;            // 512*512 bf16
  ushort* W2T     = W1T + (size_t)Hh * Hh;               // 1024*512 bf16
  ushort* pOddG   = W2T + (size_t)Vv * Hh;               // 32768*128 bf16 (8.39 MB)
  ushort* pBlankG = pOddG + (size_t)Bq * Tt * Ss;        // 32768 bf16 (+pad tail)

  transpose_cvt<<<dim3(Hh / 32, Hh / 32), dim3(32, 8), 0, stream>>>(W1, W1T, Hh, Hh);
  transpose_cvt<<<dim3(Vv / 32, Hh / 32), dim3(32, 8), 0, stream>>>(W2, W2T, Hh, Vv);
  gemm1_fused<<<dim3(Hh / 128, (Bq * Tt) / 128), dim3(256), 0, stream>>>(X, W1T, b1, h);
  gemm2sm<<<dim3((Bq * Tt) / 64), dim3(256), 0, stream>>>(h, W2T, b2, targets, pOddG, pBlankG);
  ctc_dp<<<dim3(Bq), dim3(64), 0, stream>>>(pOddG, pBlankG, targets, lens, out);
}